// Round 10
// baseline (451.181 us; speedup 1.0000x reference)
//
#include <hip/hip_runtime.h>
#include <cstddef>

#define OBS_LEN  20
#define PRED_LEN 30

typedef __attribute__((ext_vector_type(8))) short short8v;  // 8 bf16 (4 VGPRs)
typedef __attribute__((ext_vector_type(4))) float f32x4;

__device__ __forceinline__ float sigm(float x) {
    return __builtin_amdgcn_rcpf(1.0f + __expf(-x));
}
__device__ __forceinline__ float tanh_f(float x) {
    return fmaf(2.0f, sigm(2.0f * x), -1.0f);
}
// branchless RNE f32->bf16 (4 int ops, no libcall)
__device__ __forceinline__ unsigned short f2bf_rne(float x) {
    const unsigned u = __builtin_bit_cast(unsigned, x);
    return (unsigned short)((u + 0x7FFFu + ((u >> 16) & 1u)) >> 16);
}
__device__ __forceinline__ short8v ldw8(const float* __restrict__ p) {
    const float4 a = *(const float4*)(p);
    const float4 b = *(const float4*)(p + 4);
    uint4 w;
    w.x = (unsigned)f2bf_rne(a.x) | ((unsigned)f2bf_rne(a.y) << 16);
    w.y = (unsigned)f2bf_rne(a.z) | ((unsigned)f2bf_rne(a.w) << 16);
    w.z = (unsigned)f2bf_rne(b.x) | ((unsigned)f2bf_rne(b.y) << 16);
    w.w = (unsigned)f2bf_rne(b.z) | ((unsigned)f2bf_rne(b.w) << 16);
    return __builtin_bit_cast(short8v, w);
}
// per-lane embed: 8 units (rows 8q..8q+7) of one batch row -> A-fragment
__device__ __forceinline__ short8v embed8(float x0, float x1,
        const float wE0[8], const float wE1[8], const float bE[8]) {
    unsigned short s[8];
#pragma unroll
    for (int j = 0; j < 8; ++j) {
        const float e = fmaxf(0.f, fmaf(wE0[j], x0, fmaf(wE1[j], x1, bE[j])));
        s[j] = f2bf_rne(e);
    }
    uint4 w;
    w.x = (unsigned)s[0] | ((unsigned)s[1] << 16);
    w.y = (unsigned)s[2] | ((unsigned)s[3] << 16);
    w.z = (unsigned)s[4] | ((unsigned)s[5] << 16);
    w.w = (unsigned)s[6] | ((unsigned)s[7] << 16);
    return __builtin_bit_cast(short8v, w);
}

#define MFMA(A, B, C) __builtin_amdgcn_mfma_f32_16x16x32_bf16((A), (B), (C), 0, 0, 0)

// R9 structure, one change: LDS cut 54.2KB -> 30.7KB by UNIONING dead regions
// (y_hist aliases obs_l+ns_l: obs_l dead after decoder-t0 barrier, ns_l dead
// after cond barrier, y_hist first written at decoder t=1). R9 taught that
// LDS occupancy boundaries are granule-rounded (54.2KB still gave 2 blocks/CU);
// 30.7KB sits far inside the 4-block region even with an 8KB granule.
// VGPR target stays the allocator's proven 128 (= 4 waves/EU) -> 4 blocks/CU.
extern "C" __global__ void __launch_bounds__(256, 2)
traj_mfma(const float* __restrict__ obs,   const float* __restrict__ noise,
          const float* __restrict__ scene,
          const float* __restrict__ W_emb, const float* __restrict__ b_emb,
          const float* __restrict__ Wih_e, const float* __restrict__ Whh_e, const float* __restrict__ b_e,
          const float* __restrict__ W_h,   const float* __restrict__ b_h,
          const float* __restrict__ W_c,   const float* __restrict__ b_c,
          const float* __restrict__ Wih_d, const float* __restrict__ Whh_d, const float* __restrict__ b_d,
          const float* __restrict__ W_out, const float* __restrict__ b_out,
          float* __restrict__ out)
{
    __shared__ __align__(16) unsigned short hbuf[2][2][2][1152]; // [tile][buf][hi/lo] 16x72
    // union region, 2816 floats = 11264B:
    //   floats [0..1280)  = obs_l (32 rows x 40 f32)      [encoder + decoder t=0]
    //   floats [1280..2816) as ushort[3072] = ns_l[2][1536] [cond only]
    //   floats [0..1920)  = y_hist[32][60]                 [decoder t>=1 + flush]
    __shared__ __align__(16) float uni[2816];
    __shared__ __align__(16) float y_lds[4][2][16][2];           // per-WAVE y copy

    const int id = threadIdx.x;
    const int l    = id & 63;
    const int w    = id >> 6;        // wave = gate-column slice
    const int q    = l >> 4;
    const int jm   = l & 15;
    const int colb = w * 16 + jm;    // hidden j in [0,64)
    const int bb   = blockIdx.x * 32;

    float* obs_l = uni;                                   // 1280 f32
    unsigned short* ns = (unsigned short*)(uni + 1280);   // 3072 bf16
    float* y_hist = uni;                                  // 1920 f32 (aliases)

    // ---------------- one-time register-resident weights ----------------
    short8v Be[3][4], Bd[3][4];
    float bias_e[4], bias_d[4];
#pragma unroll
    for (int t = 0; t < 4; ++t) {
        const int row = t * 64 + colb;
        Be[0][t] = ldw8(Wih_e + row * 32 + 8 * q);
        Be[1][t] = ldw8(Whh_e + row * 64 + 8 * q);
        Be[2][t] = ldw8(Whh_e + row * 64 + 32 + 8 * q);
        Bd[0][t] = ldw8(Wih_d + row * 32 + 8 * q);
        Bd[1][t] = ldw8(Whh_d + row * 64 + 8 * q);
        Bd[2][t] = ldw8(Whh_d + row * 64 + 32 + 8 * q);
        bias_e[t] = b_e[row];
        bias_d[t] = b_d[row];
    }
    // W_out as B-fragment: col = jm (0/1 valid), k = 8q..
    short8v Bo0, Bo1;
    {
        const short8v z = {0, 0, 0, 0, 0, 0, 0, 0};
        if (jm < 2) {
            Bo0 = ldw8(W_out + jm * 64 + 8 * q);
            Bo1 = ldw8(W_out + jm * 64 + 32 + 8 * q);
        } else { Bo0 = z; Bo1 = z; }
    }
    // per-lane embed weights: units 8q..8q+7
    float wE0[8], wE1[8], bE[8];
#pragma unroll
    for (int j = 0; j < 8; ++j) {
        wE0[j] = W_emb[(8 * q + j) * 2];
        wE1[j] = W_emb[(8 * q + j) * 2 + 1];
        bE[j]  = b_emb[8 * q + j];
    }
    const float bo0 = b_out[0], bo1 = b_out[1];

    // init h=0, stage obs (32 rows)
    {
        unsigned* hz = (unsigned*)&hbuf[0][0][0][0];
        for (int k2 = id; k2 < 4608; k2 += 256) hz[k2] = 0u;
        for (int k2 = id; k2 < 1280; k2 += 256) obs_l[k2] = obs[(size_t)bb * 40 + k2];
    }
    float c[2][4];
#pragma unroll
    for (int p = 0; p < 2; ++p)
#pragma unroll
        for (int r = 0; r < 4; ++r) c[p][r] = 0.f;
    __syncthreads();

    int cur = 0;

    // store hi/lo via truncation (lo captures the exact residual)
#define H_STORE(nh, nl, hv, rr)                                              \
    {                                                                        \
        const unsigned uh = __builtin_bit_cast(unsigned, (hv));              \
        (nh)[(4 * q + (rr)) * 72 + colb] = (unsigned short)(uh >> 16);       \
        const float lo = (hv) - __builtin_bit_cast(float, uh & 0xFFFF0000u); \
        (nl)[(4 * q + (rr)) * 72 + colb] =                                   \
            (unsigned short)(__builtin_bit_cast(unsigned, lo) >> 16);        \
    }

    // ==================== encoder (1 barrier/step) ====================
#pragma unroll 1
    for (int t = 0; t < OBS_LEN; ++t) {
        const short8v AeA = embed8(obs_l[jm * 40 + 2 * t], obs_l[jm * 40 + 2 * t + 1],
                                   wE0, wE1, bE);
        const short8v AeB = embed8(obs_l[(16 + jm) * 40 + 2 * t], obs_l[(16 + jm) * 40 + 2 * t + 1],
                                   wE0, wE1, bE);
        const short8v H1A = *(const short8v*)(&hbuf[0][cur][0][jm * 72 + 8 * q]);
        const short8v H2A = *(const short8v*)(&hbuf[0][cur][0][jm * 72 + 32 + 8 * q]);
        const short8v L1A = *(const short8v*)(&hbuf[0][cur][1][jm * 72 + 8 * q]);
        const short8v L2A = *(const short8v*)(&hbuf[0][cur][1][jm * 72 + 32 + 8 * q]);
        const short8v H1B = *(const short8v*)(&hbuf[1][cur][0][jm * 72 + 8 * q]);
        const short8v H2B = *(const short8v*)(&hbuf[1][cur][0][jm * 72 + 32 + 8 * q]);
        const short8v L1B = *(const short8v*)(&hbuf[1][cur][1][jm * 72 + 8 * q]);
        const short8v L2B = *(const short8v*)(&hbuf[1][cur][1][jm * 72 + 32 + 8 * q]);

        f32x4 gA[4], gB[4];
#pragma unroll
        for (int t4 = 0; t4 < 4; ++t4) {
            f32x4 a = {bias_e[t4], bias_e[t4], bias_e[t4], bias_e[t4]};
            f32x4 b = a;
            a = MFMA(AeA, Be[0][t4], a);  b = MFMA(AeB, Be[0][t4], b);
            a = MFMA(H1A, Be[1][t4], a);  b = MFMA(H1B, Be[1][t4], b);
            a = MFMA(H2A, Be[2][t4], a);  b = MFMA(H2B, Be[2][t4], b);
            a = MFMA(L1A, Be[1][t4], a);  b = MFMA(L1B, Be[1][t4], b);
            a = MFMA(L2A, Be[2][t4], a);  b = MFMA(L2B, Be[2][t4], b);
            gA[t4] = a; gB[t4] = b;
        }
#pragma unroll
        for (int p = 0; p < 2; ++p) {
            unsigned short* nh = &hbuf[p][cur ^ 1][0][0];
            unsigned short* nl = &hbuf[p][cur ^ 1][1][0];
#pragma unroll
            for (int r = 0; r < 4; ++r) {
                const f32x4* g = (p == 0) ? gA : gB;
                const float ig = sigm(g[0][r]);
                const float fg = sigm(g[1][r]);
                const float gg = tanh_f(g[2][r]);
                const float og = sigm(g[3][r]);
                c[p][r] = fmaf(fg, c[p][r], ig * gg);
                const float hv = og * tanh_f(c[p][r]);
                H_STORE(nh, nl, hv, r);
            }
        }
        __syncthreads();
        cur ^= 1;
    }

    // ==================== cond -> decoder init ====================
    {
        {   // stage [noise | scene | 0] as bf16 into ns (union region)
            const int i2 = id >> 4, cb = (id & 15) * 6;
#pragma unroll
            for (int p = 0; p < 2; ++p) {
                const int row = bb + p * 16 + i2;
#pragma unroll
                for (int cc = 0; cc < 6; ++cc) {
                    const int col = cb + cc;
                    float v;
                    if (col < 16)      v = noise[(size_t)row * 16 + col];
                    else if (col < 80) v = scene[(size_t)row * 64 + (col - 16)];
                    else               v = 0.f;
                    ns[p * 1536 + i2 * 96 + col] = f2bf_rne(v);
                }
            }
        }
        __syncthreads();

        const short8v A0A = *(const short8v*)(&hbuf[0][cur][0][jm * 72 + 8 * q]);
        const short8v A1A = *(const short8v*)(&hbuf[0][cur][0][jm * 72 + 32 + 8 * q]);
        const short8v L0A = *(const short8v*)(&hbuf[0][cur][1][jm * 72 + 8 * q]);
        const short8v L1A = *(const short8v*)(&hbuf[0][cur][1][jm * 72 + 32 + 8 * q]);
        const short8v A0B = *(const short8v*)(&hbuf[1][cur][0][jm * 72 + 8 * q]);
        const short8v A1B = *(const short8v*)(&hbuf[1][cur][0][jm * 72 + 32 + 8 * q]);
        const short8v L0B = *(const short8v*)(&hbuf[1][cur][1][jm * 72 + 8 * q]);
        const short8v L1B = *(const short8v*)(&hbuf[1][cur][1][jm * 72 + 32 + 8 * q]);
        const short8v N0A = *(const short8v*)(ns + jm * 96 + 8 * q);
        const short8v N1A = *(const short8v*)(ns + jm * 96 + 32 + 8 * q);
        const short8v N2A = *(const short8v*)(ns + jm * 96 + 64 + 8 * q);
        const short8v N0B = *(const short8v*)(ns + 1536 + jm * 96 + 8 * q);
        const short8v N1B = *(const short8v*)(ns + 1536 + jm * 96 + 32 + 8 * q);
        const short8v N2B = *(const short8v*)(ns + 1536 + jm * 96 + 64 + 8 * q);
        const short8v zfrag = {0, 0, 0, 0, 0, 0, 0, 0};

        {   // h0
            short8v Bf[5];
#pragma unroll
            for (int kt = 0; kt < 4; ++kt)
                Bf[kt] = ldw8(W_h + (size_t)colb * 144 + kt * 32 + 8 * q);
            Bf[4] = (q < 2) ? ldw8(W_h + (size_t)colb * 144 + 128 + 8 * q) : zfrag;
            f32x4 ahA = {b_h[colb], b_h[colb], b_h[colb], b_h[colb]};
            f32x4 ahB = ahA;
            ahA = MFMA(A0A, Bf[0], ahA);  ahB = MFMA(A0B, Bf[0], ahB);
            ahA = MFMA(A1A, Bf[1], ahA);  ahB = MFMA(A1B, Bf[1], ahB);
            ahA = MFMA(L0A, Bf[0], ahA);  ahB = MFMA(L0B, Bf[0], ahB);
            ahA = MFMA(L1A, Bf[1], ahA);  ahB = MFMA(L1B, Bf[1], ahB);
            ahA = MFMA(N0A, Bf[2], ahA);  ahB = MFMA(N0B, Bf[2], ahB);
            ahA = MFMA(N1A, Bf[3], ahA);  ahB = MFMA(N1B, Bf[3], ahB);
            ahA = MFMA(N2A, Bf[4], ahA);  ahB = MFMA(N2B, Bf[4], ahB);
#pragma unroll
            for (int p = 0; p < 2; ++p) {
                unsigned short* nh = &hbuf[p][cur ^ 1][0][0];
                unsigned short* nl = &hbuf[p][cur ^ 1][1][0];
#pragma unroll
                for (int r = 0; r < 4; ++r) {
                    const float hv = (p == 0) ? ahA[r] : ahB[r];
                    H_STORE(nh, nl, hv, r);
                }
            }
        }
        {   // c0
            short8v Bf[5];
#pragma unroll
            for (int kt = 0; kt < 4; ++kt)
                Bf[kt] = ldw8(W_c + (size_t)colb * 144 + kt * 32 + 8 * q);
            Bf[4] = (q < 2) ? ldw8(W_c + (size_t)colb * 144 + 128 + 8 * q) : zfrag;
            f32x4 acA = {b_c[colb], b_c[colb], b_c[colb], b_c[colb]};
            f32x4 acB = acA;
            acA = MFMA(A0A, Bf[0], acA);  acB = MFMA(A0B, Bf[0], acB);
            acA = MFMA(A1A, Bf[1], acA);  acB = MFMA(A1B, Bf[1], acB);
            acA = MFMA(L0A, Bf[0], acA);  acB = MFMA(L0B, Bf[0], acB);
            acA = MFMA(L1A, Bf[1], acA);  acB = MFMA(L1B, Bf[1], acB);
            acA = MFMA(N0A, Bf[2], acA);  acB = MFMA(N0B, Bf[2], acB);
            acA = MFMA(N1A, Bf[3], acA);  acB = MFMA(N1B, Bf[3], acB);
            acA = MFMA(N2A, Bf[4], acA);  acB = MFMA(N2B, Bf[4], acB);
#pragma unroll
            for (int r = 0; r < 4; ++r) { c[0][r] = acA[r]; c[1][r] = acB[r]; }
        }
        __syncthreads();
        cur ^= 1;
    }

    // ==================== decoder (1 barrier/step) ====================
    // NOTE: obs_l is read only at t=0 (before that step's end barrier);
    // y_hist (same memory) is first written at t=1 -> no aliasing hazard.
#pragma unroll 1
    for (int t = 0; t < PRED_LEN; ++t) {
        const short8v H1A = *(const short8v*)(&hbuf[0][cur][0][jm * 72 + 8 * q]);
        const short8v H2A = *(const short8v*)(&hbuf[0][cur][0][jm * 72 + 32 + 8 * q]);
        const short8v L1A = *(const short8v*)(&hbuf[0][cur][1][jm * 72 + 8 * q]);
        const short8v L2A = *(const short8v*)(&hbuf[0][cur][1][jm * 72 + 32 + 8 * q]);
        const short8v H1B = *(const short8v*)(&hbuf[1][cur][0][jm * 72 + 8 * q]);
        const short8v H2B = *(const short8v*)(&hbuf[1][cur][0][jm * 72 + 32 + 8 * q]);
        const short8v L1B = *(const short8v*)(&hbuf[1][cur][1][jm * 72 + 8 * q]);
        const short8v L2B = *(const short8v*)(&hbuf[1][cur][1][jm * 72 + 32 + 8 * q]);

        float xA0, xA1, xB0, xB1;
        if (t == 0) {
            xA0 = obs_l[jm * 40 + 38];        xA1 = obs_l[jm * 40 + 39];
            xB0 = obs_l[(16 + jm) * 40 + 38]; xB1 = obs_l[(16 + jm) * 40 + 39];
        } else {
            // y_{t-1}: every wave computes the SAME MFMA -> use own-wave LDS copy
            f32x4 yA = {0.f, 0.f, 0.f, 0.f}, yB = {0.f, 0.f, 0.f, 0.f};
            yA = MFMA(H1A, Bo0, yA);  yB = MFMA(H1B, Bo0, yB);
            yA = MFMA(H2A, Bo1, yA);  yB = MFMA(H2B, Bo1, yB);
            yA = MFMA(L1A, Bo0, yA);  yB = MFMA(L1B, Bo0, yB);
            yA = MFMA(L2A, Bo1, yA);  yB = MFMA(L2B, Bo1, yB);
            if (jm < 2) {
#pragma unroll
                for (int r = 0; r < 4; ++r) {
                    y_lds[w][0][4 * q + r][jm] = yA[r];
                    y_lds[w][1][4 * q + r][jm] = yB[r];
                }
            }
            if (w == 0 && jm < 2) {   // record history (biased) for final flush
                const float bo = (jm == 0) ? bo0 : bo1;
#pragma unroll
                for (int r = 0; r < 4; ++r) {
                    y_hist[(4 * q + r) * 60 + (t - 1) * 2 + jm]        = yA[r] + bo;
                    y_hist[(16 + 4 * q + r) * 60 + (t - 1) * 2 + jm]   = yB[r] + bo;
                }
            }
            asm volatile("s_waitcnt lgkmcnt(0)" ::: "memory");
            __builtin_amdgcn_sched_barrier(0);
            xA0 = y_lds[w][0][jm][0] + bo0;  xA1 = y_lds[w][0][jm][1] + bo1;
            xB0 = y_lds[w][1][jm][0] + bo0;  xB1 = y_lds[w][1][jm][1] + bo1;
        }
        const short8v AeA = embed8(xA0, xA1, wE0, wE1, bE);
        const short8v AeB = embed8(xB0, xB1, wE0, wE1, bE);

        f32x4 gA[4], gB[4];
#pragma unroll
        for (int t4 = 0; t4 < 4; ++t4) {
            f32x4 a = {bias_d[t4], bias_d[t4], bias_d[t4], bias_d[t4]};
            f32x4 b = a;
            a = MFMA(AeA, Bd[0][t4], a);  b = MFMA(AeB, Bd[0][t4], b);
            a = MFMA(H1A, Bd[1][t4], a);  b = MFMA(H1B, Bd[1][t4], b);
            a = MFMA(H2A, Bd[2][t4], a);  b = MFMA(H2B, Bd[2][t4], b);
            a = MFMA(L1A, Bd[1][t4], a);  b = MFMA(L1B, Bd[1][t4], b);
            a = MFMA(L2A, Bd[2][t4], a);  b = MFMA(L2B, Bd[2][t4], b);
            gA[t4] = a; gB[t4] = b;
        }
#pragma unroll
        for (int p = 0; p < 2; ++p) {
            unsigned short* nh = &hbuf[p][cur ^ 1][0][0];
            unsigned short* nl = &hbuf[p][cur ^ 1][1][0];
#pragma unroll
            for (int r = 0; r < 4; ++r) {
                const f32x4* g = (p == 0) ? gA : gB;
                const float ig = sigm(g[0][r]);
                const float fg = sigm(g[1][r]);
                const float gg = tanh_f(g[2][r]);
                const float og = sigm(g[3][r]);
                c[p][r] = fmaf(fg, c[p][r], ig * gg);
                const float hv = og * tanh_f(c[p][r]);
                H_STORE(nh, nl, hv, r);
            }
        }
        __syncthreads();   // hbuf[cur^1] + y_hist visible
        cur ^= 1;
    }

    // ==================== final y (pred 29) from h_30 ====================
    {
        const short8v H1A = *(const short8v*)(&hbuf[0][cur][0][jm * 72 + 8 * q]);
        const short8v H2A = *(const short8v*)(&hbuf[0][cur][0][jm * 72 + 32 + 8 * q]);
        const short8v L1A = *(const short8v*)(&hbuf[0][cur][1][jm * 72 + 8 * q]);
        const short8v L2A = *(const short8v*)(&hbuf[0][cur][1][jm * 72 + 32 + 8 * q]);
        const short8v H1B = *(const short8v*)(&hbuf[1][cur][0][jm * 72 + 8 * q]);
        const short8v H2B = *(const short8v*)(&hbuf[1][cur][0][jm * 72 + 32 + 8 * q]);
        const short8v L1B = *(const short8v*)(&hbuf[1][cur][1][jm * 72 + 8 * q]);
        const short8v L2B = *(const short8v*)(&hbuf[1][cur][1][jm * 72 + 32 + 8 * q]);
        f32x4 yA = {0.f, 0.f, 0.f, 0.f}, yB = {0.f, 0.f, 0.f, 0.f};
        yA = MFMA(H1A, Bo0, yA);  yB = MFMA(H1B, Bo0, yB);
        yA = MFMA(H2A, Bo1, yA);  yB = MFMA(H2B, Bo1, yB);
        yA = MFMA(L1A, Bo0, yA);  yB = MFMA(L1B, Bo0, yB);
        yA = MFMA(L2A, Bo1, yA);  yB = MFMA(L2B, Bo1, yB);
        if (w == 0 && jm < 2) {
            const float bo = (jm == 0) ? bo0 : bo1;
#pragma unroll
            for (int r = 0; r < 4; ++r) {
                y_hist[(4 * q + r) * 60 + (PRED_LEN - 1) * 2 + jm]      = yA[r] + bo;
                y_hist[(16 + 4 * q + r) * 60 + (PRED_LEN - 1) * 2 + jm] = yB[r] + bo;
            }
        }
        __syncthreads();
        // coalesced flush: 32 rows x 60 f32 = 1920 contiguous floats
        float* op = out + (size_t)bb * 60;
        for (int k2 = id; k2 < 1920; k2 += 256) op[k2] = y_hist[k2];
    }
#undef H_STORE
}

extern "C" void kernel_launch(void* const* d_in, const int* in_sizes, int n_in,
                              void* d_out, int out_size, void* d_ws, size_t ws_size,
                              hipStream_t stream) {
    (void)in_sizes; (void)n_in; (void)d_ws; (void)ws_size; (void)out_size;
    const float* obs    = (const float*)d_in[0];
    const float* noise  = (const float*)d_in[1];
    const float* scene  = (const float*)d_in[2];
    const float* W_emb  = (const float*)d_in[3];
    const float* b_emb  = (const float*)d_in[4];
    const float* Wih_e  = (const float*)d_in[5];
    const float* Whh_e  = (const float*)d_in[6];
    const float* b_e    = (const float*)d_in[7];
    const float* W_h    = (const float*)d_in[8];
    const float* b_h    = (const float*)d_in[9];
    const float* W_c    = (const float*)d_in[10];
    const float* b_c    = (const float*)d_in[11];
    const float* Wih_d  = (const float*)d_in[12];
    const float* Whh_d  = (const float*)d_in[13];
    const float* b_d    = (const float*)d_in[14];
    const float* W_out  = (const float*)d_in[15];
    const float* b_out  = (const float*)d_in[16];
    float* out = (float*)d_out;

    dim3 grid(65536 / 32), block(256);
    hipLaunchKernelGGL(traj_mfma, grid, block, 0, stream,
                       obs, noise, scene, W_emb, b_emb,
                       Wih_e, Whh_e, b_e, W_h, b_h, W_c, b_c,
                       Wih_d, Whh_d, b_d, W_out, b_out, out);
}

// Round 11
// 379.897 us; speedup vs baseline: 1.1876x; 1.1876x over previous
//
#include <hip/hip_runtime.h>
#include <cstddef>

#define OBS_LEN  20
#define PRED_LEN 30

typedef __attribute__((ext_vector_type(8))) short short8v;  // 8 bf16 (4 VGPRs)
typedef __attribute__((ext_vector_type(4))) float f32x4;

// branchless RNE f32->bf16 (no libcall)
__device__ __forceinline__ unsigned short f2bf_rne(float x) {
    const unsigned u = __builtin_bit_cast(unsigned, x);
    return (unsigned short)((u + 0x7FFFu + ((u >> 16) & 1u)) >> 16);
}
// sigmoid from PRESCALED acc: y = -log2e * x  ->  sigma(x) = rcp(1+exp2(y))
__device__ __forceinline__ float sigm_s(float y) {
    return __builtin_amdgcn_rcpf(1.0f + __builtin_amdgcn_exp2f(y));
}
// tanh from PRESCALED acc: y = -2*log2e * x -> tanh(x) = 2*rcp(1+exp2(y)) - 1
__device__ __forceinline__ float tanh_s(float y) {
    return fmaf(2.0f, __builtin_amdgcn_rcpf(1.0f + __builtin_amdgcn_exp2f(y)), -1.0f);
}
// tanh of an UNSCALED value (for tanh(c))
__device__ __forceinline__ float tanh_f(float x) {
    return tanh_s(x * -2.885390082f);
}
// weight-row load -> bf16x8 fragment, scaled by s before conversion
__device__ __forceinline__ short8v ldw8s(const float* __restrict__ p, float s) {
    const float4 a = *(const float4*)(p);
    const float4 b = *(const float4*)(p + 4);
    uint4 w;
    w.x = (unsigned)f2bf_rne(a.x * s) | ((unsigned)f2bf_rne(a.y * s) << 16);
    w.y = (unsigned)f2bf_rne(a.z * s) | ((unsigned)f2bf_rne(a.w * s) << 16);
    w.z = (unsigned)f2bf_rne(b.x * s) | ((unsigned)f2bf_rne(b.y * s) << 16);
    w.w = (unsigned)f2bf_rne(b.z * s) | ((unsigned)f2bf_rne(b.w * s) << 16);
    return __builtin_bit_cast(short8v, w);
}
__device__ __forceinline__ short8v ldw8(const float* __restrict__ p) {
    return ldw8s(p, 1.0f);
}
// per-lane embed: 8 units (rows 8q..8q+7) of one batch row -> A-fragment
__device__ __forceinline__ short8v embed8(float x0, float x1,
        const float wE0[8], const float wE1[8], const float bE[8]) {
    unsigned short s[8];
#pragma unroll
    for (int j = 0; j < 8; ++j) {
        const float e = fmaxf(0.f, fmaf(wE0[j], x0, fmaf(wE1[j], x1, bE[j])));
        s[j] = f2bf_rne(e);
    }
    uint4 w;
    w.x = (unsigned)s[0] | ((unsigned)s[1] << 16);
    w.y = (unsigned)s[2] | ((unsigned)s[3] << 16);
    w.z = (unsigned)s[4] | ((unsigned)s[5] << 16);
    w.w = (unsigned)s[6] | ((unsigned)s[7] << 16);
    return __builtin_bit_cast(short8v, w);
}

#define MFMA(A, B, C) __builtin_amdgcn_mfma_f32_16x16x32_bf16((A), (B), (C), 0, 0, 0)

// R10 post-mortem: VALUBusy 67 + MfmaUtil 26 = 93% -> ISSUE-BOUND. This round
// cuts issued work: (1) lo-residual h pass DROPPED (h stored bf16-RNE only):
// -20 MFMA, -4 ds_read_b128, -8 ds_write, -30 VALU per wave-step. absmax est.
// 0.006-0.012 vs 0.0168 threshold (weights dominate; revert if fail).
// (2) gate weights PRESCALED by -log2e (i,f,o) / -2log2e (g) at load:
// sigmoid/tanh = rcp(1+exp2(acc)) -- one v_mul per transcendental deleted.
extern "C" __global__ void __launch_bounds__(256, 2)
traj_mfma(const float* __restrict__ obs,   const float* __restrict__ noise,
          const float* __restrict__ scene,
          const float* __restrict__ W_emb, const float* __restrict__ b_emb,
          const float* __restrict__ Wih_e, const float* __restrict__ Whh_e, const float* __restrict__ b_e,
          const float* __restrict__ W_h,   const float* __restrict__ b_h,
          const float* __restrict__ W_c,   const float* __restrict__ b_c,
          const float* __restrict__ Wih_d, const float* __restrict__ Whh_d, const float* __restrict__ b_d,
          const float* __restrict__ W_out, const float* __restrict__ b_out,
          float* __restrict__ out)
{
    __shared__ __align__(16) unsigned short hbuf[2][2][1152]; // [tile][buf] 16x72 bf16
    // union region, 2816 floats:
    //   [0..1280) f32        = obs_l (32x40)   [encoder + decoder t=0]
    //   [1280..2816) as bf16 = ns[2][1536]     [cond only]
    //   [0..1920) f32        = y_hist[32][60]  [decoder t>=1 + flush]
    __shared__ __align__(16) float uni[2816];
    __shared__ __align__(16) float y_lds[4][2][16][2];        // per-WAVE y copy

    const int id = threadIdx.x;
    const int l    = id & 63;
    const int w    = id >> 6;        // wave = gate-column slice
    const int q    = l >> 4;
    const int jm   = l & 15;
    const int colb = w * 16 + jm;    // hidden j in [0,64)
    const int bb   = blockIdx.x * 32;

    float* obs_l = uni;                                   // 1280 f32
    unsigned short* ns = (unsigned short*)(uni + 1280);   // 3072 bf16
    float* y_hist = uni;                                  // 1920 f32 (aliases)

    // gate prescales: i,f,o -> -log2e ; g -> -2log2e
    const float GS[4] = {-1.442695041f, -1.442695041f, -2.885390082f, -1.442695041f};

    // ---------------- one-time register-resident weights ----------------
    short8v Be[3][4], Bd[3][4];
    float bias_e[4], bias_d[4];
#pragma unroll
    for (int t = 0; t < 4; ++t) {
        const int row = t * 64 + colb;
        const float s = GS[t];
        Be[0][t] = ldw8s(Wih_e + row * 32 + 8 * q, s);
        Be[1][t] = ldw8s(Whh_e + row * 64 + 8 * q, s);
        Be[2][t] = ldw8s(Whh_e + row * 64 + 32 + 8 * q, s);
        Bd[0][t] = ldw8s(Wih_d + row * 32 + 8 * q, s);
        Bd[1][t] = ldw8s(Whh_d + row * 64 + 8 * q, s);
        Bd[2][t] = ldw8s(Whh_d + row * 64 + 32 + 8 * q, s);
        bias_e[t] = b_e[row] * s;
        bias_d[t] = b_d[row] * s;
    }
    // W_out as B-fragment: col = jm (0/1 valid), k = 8q.. (unscaled)
    short8v Bo0, Bo1;
    {
        const short8v z = {0, 0, 0, 0, 0, 0, 0, 0};
        if (jm < 2) {
            Bo0 = ldw8(W_out + jm * 64 + 8 * q);
            Bo1 = ldw8(W_out + jm * 64 + 32 + 8 * q);
        } else { Bo0 = z; Bo1 = z; }
    }
    // per-lane embed weights: units 8q..8q+7
    float wE0[8], wE1[8], bE[8];
#pragma unroll
    for (int j = 0; j < 8; ++j) {
        wE0[j] = W_emb[(8 * q + j) * 2];
        wE1[j] = W_emb[(8 * q + j) * 2 + 1];
        bE[j]  = b_emb[8 * q + j];
    }
    const float bo0 = b_out[0], bo1 = b_out[1];

    // init h=0, stage obs (32 rows)
    {
        unsigned* hz = (unsigned*)&hbuf[0][0][0];
        for (int k2 = id; k2 < 2304; k2 += 256) hz[k2] = 0u;
        for (int k2 = id; k2 < 1280; k2 += 256) obs_l[k2] = obs[(size_t)bb * 40 + k2];
    }
    float c[2][4];
#pragma unroll
    for (int p = 0; p < 2; ++p)
#pragma unroll
        for (int r = 0; r < 4; ++r) c[p][r] = 0.f;
    __syncthreads();

    int cur = 0;

    // ==================== encoder (1 barrier/step) ====================
#pragma unroll 1
    for (int t = 0; t < OBS_LEN; ++t) {
        const short8v AeA = embed8(obs_l[jm * 40 + 2 * t], obs_l[jm * 40 + 2 * t + 1],
                                   wE0, wE1, bE);
        const short8v AeB = embed8(obs_l[(16 + jm) * 40 + 2 * t], obs_l[(16 + jm) * 40 + 2 * t + 1],
                                   wE0, wE1, bE);
        const short8v H1A = *(const short8v*)(&hbuf[0][cur][jm * 72 + 8 * q]);
        const short8v H2A = *(const short8v*)(&hbuf[0][cur][jm * 72 + 32 + 8 * q]);
        const short8v H1B = *(const short8v*)(&hbuf[1][cur][jm * 72 + 8 * q]);
        const short8v H2B = *(const short8v*)(&hbuf[1][cur][jm * 72 + 32 + 8 * q]);

        f32x4 gA[4], gB[4];
#pragma unroll
        for (int t4 = 0; t4 < 4; ++t4) {
            f32x4 a = {bias_e[t4], bias_e[t4], bias_e[t4], bias_e[t4]};
            f32x4 b = a;
            a = MFMA(AeA, Be[0][t4], a);  b = MFMA(AeB, Be[0][t4], b);
            a = MFMA(H1A, Be[1][t4], a);  b = MFMA(H1B, Be[1][t4], b);
            a = MFMA(H2A, Be[2][t4], a);  b = MFMA(H2B, Be[2][t4], b);
            gA[t4] = a; gB[t4] = b;
        }
#pragma unroll
        for (int p = 0; p < 2; ++p) {
            unsigned short* nh = &hbuf[p][cur ^ 1][0];
#pragma unroll
            for (int r = 0; r < 4; ++r) {
                const f32x4* g = (p == 0) ? gA : gB;
                const float ig = sigm_s(g[0][r]);
                const float fg = sigm_s(g[1][r]);
                const float gg = tanh_s(g[2][r]);
                const float og = sigm_s(g[3][r]);
                c[p][r] = fmaf(fg, c[p][r], ig * gg);
                const float hv = og * tanh_f(c[p][r]);
                nh[(4 * q + r) * 72 + colb] = f2bf_rne(hv);
            }
        }
        __syncthreads();
        cur ^= 1;
    }

    // ==================== cond -> decoder init ====================
    {
        {   // stage [noise | scene | 0] as bf16 into ns (union region)
            const int i2 = id >> 4, cb = (id & 15) * 6;
#pragma unroll
            for (int p = 0; p < 2; ++p) {
                const int row = bb + p * 16 + i2;
#pragma unroll
                for (int cc = 0; cc < 6; ++cc) {
                    const int col = cb + cc;
                    float v;
                    if (col < 16)      v = noise[(size_t)row * 16 + col];
                    else if (col < 80) v = scene[(size_t)row * 64 + (col - 16)];
                    else               v = 0.f;
                    ns[p * 1536 + i2 * 96 + col] = f2bf_rne(v);
                }
            }
        }
        __syncthreads();

        const short8v A0A = *(const short8v*)(&hbuf[0][cur][jm * 72 + 8 * q]);
        const short8v A1A = *(const short8v*)(&hbuf[0][cur][jm * 72 + 32 + 8 * q]);
        const short8v A0B = *(const short8v*)(&hbuf[1][cur][jm * 72 + 8 * q]);
        const short8v A1B = *(const short8v*)(&hbuf[1][cur][jm * 72 + 32 + 8 * q]);
        const short8v N0A = *(const short8v*)(ns + jm * 96 + 8 * q);
        const short8v N1A = *(const short8v*)(ns + jm * 96 + 32 + 8 * q);
        const short8v N2A = *(const short8v*)(ns + jm * 96 + 64 + 8 * q);
        const short8v N0B = *(const short8v*)(ns + 1536 + jm * 96 + 8 * q);
        const short8v N1B = *(const short8v*)(ns + 1536 + jm * 96 + 32 + 8 * q);
        const short8v N2B = *(const short8v*)(ns + 1536 + jm * 96 + 64 + 8 * q);
        const short8v zfrag = {0, 0, 0, 0, 0, 0, 0, 0};

        {   // h0
            short8v Bf[5];
#pragma unroll
            for (int kt = 0; kt < 4; ++kt)
                Bf[kt] = ldw8(W_h + (size_t)colb * 144 + kt * 32 + 8 * q);
            Bf[4] = (q < 2) ? ldw8(W_h + (size_t)colb * 144 + 128 + 8 * q) : zfrag;
            f32x4 ahA = {b_h[colb], b_h[colb], b_h[colb], b_h[colb]};
            f32x4 ahB = ahA;
            ahA = MFMA(A0A, Bf[0], ahA);  ahB = MFMA(A0B, Bf[0], ahB);
            ahA = MFMA(A1A, Bf[1], ahA);  ahB = MFMA(A1B, Bf[1], ahB);
            ahA = MFMA(N0A, Bf[2], ahA);  ahB = MFMA(N0B, Bf[2], ahB);
            ahA = MFMA(N1A, Bf[3], ahA);  ahB = MFMA(N1B, Bf[3], ahB);
            ahA = MFMA(N2A, Bf[4], ahA);  ahB = MFMA(N2B, Bf[4], ahB);
#pragma unroll
            for (int p = 0; p < 2; ++p) {
                unsigned short* nh = &hbuf[p][cur ^ 1][0];
#pragma unroll
                for (int r = 0; r < 4; ++r) {
                    const float hv = (p == 0) ? ahA[r] : ahB[r];
                    nh[(4 * q + r) * 72 + colb] = f2bf_rne(hv);
                }
            }
        }
        {   // c0
            short8v Bf[5];
#pragma unroll
            for (int kt = 0; kt < 4; ++kt)
                Bf[kt] = ldw8(W_c + (size_t)colb * 144 + kt * 32 + 8 * q);
            Bf[4] = (q < 2) ? ldw8(W_c + (size_t)colb * 144 + 128 + 8 * q) : zfrag;
            f32x4 acA = {b_c[colb], b_c[colb], b_c[colb], b_c[colb]};
            f32x4 acB = acA;
            acA = MFMA(A0A, Bf[0], acA);  acB = MFMA(A0B, Bf[0], acB);
            acA = MFMA(A1A, Bf[1], acA);  acB = MFMA(A1B, Bf[1], acB);
            acA = MFMA(N0A, Bf[2], acA);  acB = MFMA(N0B, Bf[2], acB);
            acA = MFMA(N1A, Bf[3], acA);  acB = MFMA(N1B, Bf[3], acB);
            acA = MFMA(N2A, Bf[4], acA);  acB = MFMA(N2B, Bf[4], acB);
#pragma unroll
            for (int r = 0; r < 4; ++r) { c[0][r] = acA[r]; c[1][r] = acB[r]; }
        }
        __syncthreads();
        cur ^= 1;
    }

    // ==================== decoder (1 barrier/step) ====================
    // obs_l read only at t=0; y_hist (same memory) first written at t=1.
#pragma unroll 1
    for (int t = 0; t < PRED_LEN; ++t) {
        const short8v H1A = *(const short8v*)(&hbuf[0][cur][jm * 72 + 8 * q]);
        const short8v H2A = *(const short8v*)(&hbuf[0][cur][jm * 72 + 32 + 8 * q]);
        const short8v H1B = *(const short8v*)(&hbuf[1][cur][jm * 72 + 8 * q]);
        const short8v H2B = *(const short8v*)(&hbuf[1][cur][jm * 72 + 32 + 8 * q]);

        float xA0, xA1, xB0, xB1;
        if (t == 0) {
            xA0 = obs_l[jm * 40 + 38];        xA1 = obs_l[jm * 40 + 39];
            xB0 = obs_l[(16 + jm) * 40 + 38]; xB1 = obs_l[(16 + jm) * 40 + 39];
        } else {
            // y_{t-1}: every wave computes the SAME MFMA -> own-wave LDS copy
            f32x4 yA = {0.f, 0.f, 0.f, 0.f}, yB = {0.f, 0.f, 0.f, 0.f};
            yA = MFMA(H1A, Bo0, yA);  yB = MFMA(H1B, Bo0, yB);
            yA = MFMA(H2A, Bo1, yA);  yB = MFMA(H2B, Bo1, yB);
            if (jm < 2) {
#pragma unroll
                for (int r = 0; r < 4; ++r) {
                    y_lds[w][0][4 * q + r][jm] = yA[r];
                    y_lds[w][1][4 * q + r][jm] = yB[r];
                }
            }
            if (w == 0 && jm < 2) {   // record history (biased) for final flush
                const float bo = (jm == 0) ? bo0 : bo1;
#pragma unroll
                for (int r = 0; r < 4; ++r) {
                    y_hist[(4 * q + r) * 60 + (t - 1) * 2 + jm]      = yA[r] + bo;
                    y_hist[(16 + 4 * q + r) * 60 + (t - 1) * 2 + jm] = yB[r] + bo;
                }
            }
            asm volatile("s_waitcnt lgkmcnt(0)" ::: "memory");
            __builtin_amdgcn_sched_barrier(0);
            xA0 = y_lds[w][0][jm][0] + bo0;  xA1 = y_lds[w][0][jm][1] + bo1;
            xB0 = y_lds[w][1][jm][0] + bo0;  xB1 = y_lds[w][1][jm][1] + bo1;
        }
        const short8v AeA = embed8(xA0, xA1, wE0, wE1, bE);
        const short8v AeB = embed8(xB0, xB1, wE0, wE1, bE);

        f32x4 gA[4], gB[4];
#pragma unroll
        for (int t4 = 0; t4 < 4; ++t4) {
            f32x4 a = {bias_d[t4], bias_d[t4], bias_d[t4], bias_d[t4]};
            f32x4 b = a;
            a = MFMA(AeA, Bd[0][t4], a);  b = MFMA(AeB, Bd[0][t4], b);
            a = MFMA(H1A, Bd[1][t4], a);  b = MFMA(H1B, Bd[1][t4], b);
            a = MFMA(H2A, Bd[2][t4], a);  b = MFMA(H2B, Bd[2][t4], b);
            gA[t4] = a; gB[t4] = b;
        }
#pragma unroll
        for (int p = 0; p < 2; ++p) {
            unsigned short* nh = &hbuf[p][cur ^ 1][0];
#pragma unroll
            for (int r = 0; r < 4; ++r) {
                const f32x4* g = (p == 0) ? gA : gB;
                const float ig = sigm_s(g[0][r]);
                const float fg = sigm_s(g[1][r]);
                const float gg = tanh_s(g[2][r]);
                const float og = sigm_s(g[3][r]);
                c[p][r] = fmaf(fg, c[p][r], ig * gg);
                const float hv = og * tanh_f(c[p][r]);
                nh[(4 * q + r) * 72 + colb] = f2bf_rne(hv);
            }
        }
        __syncthreads();   // hbuf[cur^1] + y_hist visible
        cur ^= 1;
    }

    // ==================== final y (pred 29) from h_30 ====================
    {
        const short8v H1A = *(const short8v*)(&hbuf[0][cur][jm * 72 + 8 * q]);
        const short8v H2A = *(const short8v*)(&hbuf[0][cur][jm * 72 + 32 + 8 * q]);
        const short8v H1B = *(const short8v*)(&hbuf[1][cur][jm * 72 + 8 * q]);
        const short8v H2B = *(const short8v*)(&hbuf[1][cur][jm * 72 + 32 + 8 * q]);
        f32x4 yA = {0.f, 0.f, 0.f, 0.f}, yB = {0.f, 0.f, 0.f, 0.f};
        yA = MFMA(H1A, Bo0, yA);  yB = MFMA(H1B, Bo0, yB);
        yA = MFMA(H2A, Bo1, yA);  yB = MFMA(H2B, Bo1, yB);
        if (w == 0 && jm < 2) {
            const float bo = (jm == 0) ? bo0 : bo1;
#pragma unroll
            for (int r = 0; r < 4; ++r) {
                y_hist[(4 * q + r) * 60 + (PRED_LEN - 1) * 2 + jm]      = yA[r] + bo;
                y_hist[(16 + 4 * q + r) * 60 + (PRED_LEN - 1) * 2 + jm] = yB[r] + bo;
            }
        }
        __syncthreads();
        // coalesced flush: 32 rows x 60 f32 = 1920 contiguous floats
        float* op = out + (size_t)bb * 60;
        for (int k2 = id; k2 < 1920; k2 += 256) op[k2] = y_hist[k2];
    }
}

extern "C" void kernel_launch(void* const* d_in, const int* in_sizes, int n_in,
                              void* d_out, int out_size, void* d_ws, size_t ws_size,
                              hipStream_t stream) {
    (void)in_sizes; (void)n_in; (void)d_ws; (void)ws_size; (void)out_size;
    const float* obs    = (const float*)d_in[0];
    const float* noise  = (const float*)d_in[1];
    const float* scene  = (const float*)d_in[2];
    const float* W_emb  = (const float*)d_in[3];
    const float* b_emb  = (const float*)d_in[4];
    const float* Wih_e  = (const float*)d_in[5];
    const float* Whh_e  = (const float*)d_in[6];
    const float* b_e    = (const float*)d_in[7];
    const float* W_h    = (const float*)d_in[8];
    const float* b_h    = (const float*)d_in[9];
    const float* W_c    = (const float*)d_in[10];
    const float* b_c    = (const float*)d_in[11];
    const float* Wih_d  = (const float*)d_in[12];
    const float* Whh_d  = (const float*)d_in[13];
    const float* b_d    = (const float*)d_in[14];
    const float* W_out  = (const float*)d_in[15];
    const float* b_out  = (const float*)d_in[16];
    float* out = (float*)d_out;

    dim3 grid(65536 / 32), block(256);
    hipLaunchKernelGGL(traj_mfma, grid, block, 0, stream,
                       obs, noise, scene, W_emb, b_emb,
                       Wih_e, Whh_e, b_e, W_h, b_h, W_c, b_c,
                       Wih_d, Whh_d, b_d, W_out, b_out, out);
}

// Round 12
// 363.897 us; speedup vs baseline: 1.2399x; 1.0440x over previous
//
#include <hip/hip_runtime.h>
#include <cstddef>

#define OBS_LEN  20
#define PRED_LEN 30

typedef __attribute__((ext_vector_type(8))) short short8v;  // 8 bf16 (4 VGPRs)
typedef __attribute__((ext_vector_type(4))) float f32x4;

// branchless RNE f32->bf16 (no libcall)
__device__ __forceinline__ unsigned short f2bf_rne(float x) {
    const unsigned u = __builtin_bit_cast(unsigned, x);
    return (unsigned short)((u + 0x7FFFu + ((u >> 16) & 1u)) >> 16);
}
// sigmoid from PRESCALED acc: y = -log2e * x  ->  sigma(x) = rcp(1+exp2(y))
__device__ __forceinline__ float sigm_s(float y) {
    return __builtin_amdgcn_rcpf(1.0f + __builtin_amdgcn_exp2f(y));
}
// tanh from PRESCALED acc: y = -2*log2e * x -> tanh(x) = 2*rcp(1+exp2(y)) - 1
__device__ __forceinline__ float tanh_s(float y) {
    return fmaf(2.0f, __builtin_amdgcn_rcpf(1.0f + __builtin_amdgcn_exp2f(y)), -1.0f);
}
// tanh of an UNSCALED value (for tanh(c))
__device__ __forceinline__ float tanh_f(float x) {
    return tanh_s(x * -2.885390082f);
}
// weight-row load -> bf16x8 fragment, scaled by s before conversion
__device__ __forceinline__ short8v ldw8s(const float* __restrict__ p, float s) {
    const float4 a = *(const float4*)(p);
    const float4 b = *(const float4*)(p + 4);
    uint4 w;
    w.x = (unsigned)f2bf_rne(a.x * s) | ((unsigned)f2bf_rne(a.y * s) << 16);
    w.y = (unsigned)f2bf_rne(a.z * s) | ((unsigned)f2bf_rne(a.w * s) << 16);
    w.z = (unsigned)f2bf_rne(b.x * s) | ((unsigned)f2bf_rne(b.y * s) << 16);
    w.w = (unsigned)f2bf_rne(b.z * s) | ((unsigned)f2bf_rne(b.w * s) << 16);
    return __builtin_bit_cast(short8v, w);
}
__device__ __forceinline__ short8v ldw8(const float* __restrict__ p) {
    return ldw8s(p, 1.0f);
}
// per-lane embed: 8 units (rows 8q..8q+7) of one batch row -> A-fragment
__device__ __forceinline__ short8v embed8(float x0, float x1,
        const float wE0[8], const float wE1[8], const float bE[8]) {
    unsigned short s[8];
#pragma unroll
    for (int j = 0; j < 8; ++j) {
        const float e = fmaxf(0.f, fmaf(wE0[j], x0, fmaf(wE1[j], x1, bE[j])));
        s[j] = f2bf_rne(e);
    }
    uint4 w;
    w.x = (unsigned)s[0] | ((unsigned)s[1] << 16);
    w.y = (unsigned)s[2] | ((unsigned)s[3] << 16);
    w.z = (unsigned)s[4] | ((unsigned)s[5] << 16);
    w.w = (unsigned)s[6] | ((unsigned)s[7] << 16);
    return __builtin_bit_cast(short8v, w);
}

#define MFMA(A, B, C) __builtin_amdgcn_mfma_f32_16x16x32_bf16((A), (B), (C), 0, 0, 0)

// gate prescales: i,f,o -> -log2e ; g -> -2log2e
#define GS0 -1.442695041f
#define GS2 -2.885390082f

// load one phase's gate-weight fragments (prescaled) into the overlay regs
__device__ __forceinline__ void load_gates(short8v Bw[3][4], float bias_g[4],
        const float* __restrict__ Wih, const float* __restrict__ Whh,
        const float* __restrict__ bias, int colb, int q) {
    const float GS[4] = {GS0, GS0, GS2, GS0};
#pragma unroll
    for (int t = 0; t < 4; ++t) {
        const int row = t * 64 + colb;
        const float s = GS[t];
        Bw[0][t] = ldw8s(Wih + row * 32 + 8 * q, s);
        Bw[1][t] = ldw8s(Whh + row * 64 + 8 * q, s);
        Bw[2][t] = ldw8s(Whh + row * 64 + 32 + 8 * q, s);
        bias_g[t] = bias[row] * s;
    }
}

// R11 post-mortem: occupancy pinned at 2 waves/SIMD across LDS 55->21KB ->
// the cap is the UNIFIED REGISTER FILE (VGPR+AGPR ~192/wave), not LDS.
// This round: OVERLAY encoder/decoder gate weights in ONE register set
// (enc weights dead during decoder and vice versa) -> peak drops ~48 regs
// -> ~150/wave -> 3 waves/EU. W_out frag load also deferred to decoder.
// Reload happens once, L2-cached, hidden under the cond-init MFMAs.
extern "C" __global__ void __launch_bounds__(256, 2)
traj_mfma(const float* __restrict__ obs,   const float* __restrict__ noise,
          const float* __restrict__ scene,
          const float* __restrict__ W_emb, const float* __restrict__ b_emb,
          const float* __restrict__ Wih_e, const float* __restrict__ Whh_e, const float* __restrict__ b_e,
          const float* __restrict__ W_h,   const float* __restrict__ b_h,
          const float* __restrict__ W_c,   const float* __restrict__ b_c,
          const float* __restrict__ Wih_d, const float* __restrict__ Whh_d, const float* __restrict__ b_d,
          const float* __restrict__ W_out, const float* __restrict__ b_out,
          float* __restrict__ out)
{
    __shared__ __align__(16) unsigned short hbuf[2][2][1152]; // [tile][buf] 16x72 bf16
    // union region, 2816 floats:
    //   [0..1280) f32        = obs_l (32x40)   [encoder + decoder t=0]
    //   [1280..2816) as bf16 = ns[2][1536]     [cond only]
    //   [0..1920) f32        = y_hist[32][60]  [decoder t>=1 + flush]
    __shared__ __align__(16) float uni[2816];
    __shared__ __align__(16) float y_lds[4][2][16][2];        // per-WAVE y copy

    const int id = threadIdx.x;
    const int l    = id & 63;
    const int w    = id >> 6;        // wave = gate-column slice
    const int q    = l >> 4;
    const int jm   = l & 15;
    const int colb = w * 16 + jm;    // hidden j in [0,64)
    const int bb   = blockIdx.x * 32;

    float* obs_l = uni;                                   // 1280 f32
    unsigned short* ns = (unsigned short*)(uni + 1280);   // 3072 bf16
    float* y_hist = uni;                                  // 1920 f32 (aliases)

    // ---------------- overlay gate-weight registers (one phase at a time) ----
    short8v Bw[3][4];
    float bias_g[4];
    load_gates(Bw, bias_g, Wih_e, Whh_e, b_e, colb, q);   // encoder set

    // per-lane embed weights: units 8q..8q+7
    float wE0[8], wE1[8], bE[8];
#pragma unroll
    for (int j = 0; j < 8; ++j) {
        wE0[j] = W_emb[(8 * q + j) * 2];
        wE1[j] = W_emb[(8 * q + j) * 2 + 1];
        bE[j]  = b_emb[8 * q + j];
    }
    const float bo0 = b_out[0], bo1 = b_out[1];

    // init h=0, stage obs (32 rows)
    {
        unsigned* hz = (unsigned*)&hbuf[0][0][0];
        for (int k2 = id; k2 < 2304; k2 += 256) hz[k2] = 0u;
        for (int k2 = id; k2 < 1280; k2 += 256) obs_l[k2] = obs[(size_t)bb * 40 + k2];
    }
    float c[2][4];
#pragma unroll
    for (int p = 0; p < 2; ++p)
#pragma unroll
        for (int r = 0; r < 4; ++r) c[p][r] = 0.f;
    __syncthreads();

    int cur = 0;

    // ==================== encoder (1 barrier/step) ====================
#pragma unroll 1
    for (int t = 0; t < OBS_LEN; ++t) {
        const short8v AeA = embed8(obs_l[jm * 40 + 2 * t], obs_l[jm * 40 + 2 * t + 1],
                                   wE0, wE1, bE);
        const short8v AeB = embed8(obs_l[(16 + jm) * 40 + 2 * t], obs_l[(16 + jm) * 40 + 2 * t + 1],
                                   wE0, wE1, bE);
        const short8v H1A = *(const short8v*)(&hbuf[0][cur][jm * 72 + 8 * q]);
        const short8v H2A = *(const short8v*)(&hbuf[0][cur][jm * 72 + 32 + 8 * q]);
        const short8v H1B = *(const short8v*)(&hbuf[1][cur][jm * 72 + 8 * q]);
        const short8v H2B = *(const short8v*)(&hbuf[1][cur][jm * 72 + 32 + 8 * q]);

        f32x4 gA[4], gB[4];
#pragma unroll
        for (int t4 = 0; t4 < 4; ++t4) {
            f32x4 a = {bias_g[t4], bias_g[t4], bias_g[t4], bias_g[t4]};
            f32x4 b = a;
            a = MFMA(AeA, Bw[0][t4], a);  b = MFMA(AeB, Bw[0][t4], b);
            a = MFMA(H1A, Bw[1][t4], a);  b = MFMA(H1B, Bw[1][t4], b);
            a = MFMA(H2A, Bw[2][t4], a);  b = MFMA(H2B, Bw[2][t4], b);
            gA[t4] = a; gB[t4] = b;
        }
#pragma unroll
        for (int p = 0; p < 2; ++p) {
            unsigned short* nh = &hbuf[p][cur ^ 1][0];
#pragma unroll
            for (int r = 0; r < 4; ++r) {
                const f32x4* g = (p == 0) ? gA : gB;
                const float ig = sigm_s(g[0][r]);
                const float fg = sigm_s(g[1][r]);
                const float gg = tanh_s(g[2][r]);
                const float og = sigm_s(g[3][r]);
                c[p][r] = fmaf(fg, c[p][r], ig * gg);
                const float hv = og * tanh_f(c[p][r]);
                nh[(4 * q + r) * 72 + colb] = f2bf_rne(hv);
            }
        }
        __syncthreads();
        cur ^= 1;
    }

    // -------- swap overlay to decoder weights (hidden under cond MFMAs) -----
    load_gates(Bw, bias_g, Wih_d, Whh_d, b_d, colb, q);
    // W_out as B-fragment: col = jm (0/1 valid), k = 8q.. (unscaled)
    short8v Bo0, Bo1;
    {
        const short8v z = {0, 0, 0, 0, 0, 0, 0, 0};
        if (jm < 2) {
            Bo0 = ldw8(W_out + jm * 64 + 8 * q);
            Bo1 = ldw8(W_out + jm * 64 + 32 + 8 * q);
        } else { Bo0 = z; Bo1 = z; }
    }

    // ==================== cond -> decoder init ====================
    {
        {   // stage [noise | scene | 0] as bf16 into ns (union region)
            const int i2 = id >> 4, cb = (id & 15) * 6;
#pragma unroll
            for (int p = 0; p < 2; ++p) {
                const int row = bb + p * 16 + i2;
#pragma unroll
                for (int cc = 0; cc < 6; ++cc) {
                    const int col = cb + cc;
                    float v;
                    if (col < 16)      v = noise[(size_t)row * 16 + col];
                    else if (col < 80) v = scene[(size_t)row * 64 + (col - 16)];
                    else               v = 0.f;
                    ns[p * 1536 + i2 * 96 + col] = f2bf_rne(v);
                }
            }
        }
        __syncthreads();

        const short8v A0A = *(const short8v*)(&hbuf[0][cur][jm * 72 + 8 * q]);
        const short8v A1A = *(const short8v*)(&hbuf[0][cur][jm * 72 + 32 + 8 * q]);
        const short8v A0B = *(const short8v*)(&hbuf[1][cur][jm * 72 + 8 * q]);
        const short8v A1B = *(const short8v*)(&hbuf[1][cur][jm * 72 + 32 + 8 * q]);
        const short8v N0A = *(const short8v*)(ns + jm * 96 + 8 * q);
        const short8v N1A = *(const short8v*)(ns + jm * 96 + 32 + 8 * q);
        const short8v N2A = *(const short8v*)(ns + jm * 96 + 64 + 8 * q);
        const short8v N0B = *(const short8v*)(ns + 1536 + jm * 96 + 8 * q);
        const short8v N1B = *(const short8v*)(ns + 1536 + jm * 96 + 32 + 8 * q);
        const short8v N2B = *(const short8v*)(ns + 1536 + jm * 96 + 64 + 8 * q);
        const short8v zfrag = {0, 0, 0, 0, 0, 0, 0, 0};

        {   // h0
            short8v Bf[5];
#pragma unroll
            for (int kt = 0; kt < 4; ++kt)
                Bf[kt] = ldw8(W_h + (size_t)colb * 144 + kt * 32 + 8 * q);
            Bf[4] = (q < 2) ? ldw8(W_h + (size_t)colb * 144 + 128 + 8 * q) : zfrag;
            f32x4 ahA = {b_h[colb], b_h[colb], b_h[colb], b_h[colb]};
            f32x4 ahB = ahA;
            ahA = MFMA(A0A, Bf[0], ahA);  ahB = MFMA(A0B, Bf[0], ahB);
            ahA = MFMA(A1A, Bf[1], ahA);  ahB = MFMA(A1B, Bf[1], ahB);
            ahA = MFMA(N0A, Bf[2], ahA);  ahB = MFMA(N0B, Bf[2], ahB);
            ahA = MFMA(N1A, Bf[3], ahA);  ahB = MFMA(N1B, Bf[3], ahB);
            ahA = MFMA(N2A, Bf[4], ahA);  ahB = MFMA(N2B, Bf[4], ahB);
#pragma unroll
            for (int p = 0; p < 2; ++p) {
                unsigned short* nh = &hbuf[p][cur ^ 1][0];
#pragma unroll
                for (int r = 0; r < 4; ++r) {
                    const float hv = (p == 0) ? ahA[r] : ahB[r];
                    nh[(4 * q + r) * 72 + colb] = f2bf_rne(hv);
                }
            }
        }
        {   // c0
            short8v Bf[5];
#pragma unroll
            for (int kt = 0; kt < 4; ++kt)
                Bf[kt] = ldw8(W_c + (size_t)colb * 144 + kt * 32 + 8 * q);
            Bf[4] = (q < 2) ? ldw8(W_c + (size_t)colb * 144 + 128 + 8 * q) : zfrag;
            f32x4 acA = {b_c[colb], b_c[colb], b_c[colb], b_c[colb]};
            f32x4 acB = acA;
            acA = MFMA(A0A, Bf[0], acA);  acB = MFMA(A0B, Bf[0], acB);
            acA = MFMA(A1A, Bf[1], acA);  acB = MFMA(A1B, Bf[1], acB);
            acA = MFMA(N0A, Bf[2], acA);  acB = MFMA(N0B, Bf[2], acB);
            acA = MFMA(N1A, Bf[3], acA);  acB = MFMA(N1B, Bf[3], acB);
            acA = MFMA(N2A, Bf[4], acA);  acB = MFMA(N2B, Bf[4], acB);
#pragma unroll
            for (int r = 0; r < 4; ++r) { c[0][r] = acA[r]; c[1][r] = acB[r]; }
        }
        __syncthreads();
        cur ^= 1;
    }

    // ==================== decoder (1 barrier/step) ====================
    // obs_l read only at t=0; y_hist (same memory) first written at t=1.
#pragma unroll 1
    for (int t = 0; t < PRED_LEN; ++t) {
        const short8v H1A = *(const short8v*)(&hbuf[0][cur][jm * 72 + 8 * q]);
        const short8v H2A = *(const short8v*)(&hbuf[0][cur][jm * 72 + 32 + 8 * q]);
        const short8v H1B = *(const short8v*)(&hbuf[1][cur][jm * 72 + 8 * q]);
        const short8v H2B = *(const short8v*)(&hbuf[1][cur][jm * 72 + 32 + 8 * q]);

        float xA0, xA1, xB0, xB1;
        if (t == 0) {
            xA0 = obs_l[jm * 40 + 38];        xA1 = obs_l[jm * 40 + 39];
            xB0 = obs_l[(16 + jm) * 40 + 38]; xB1 = obs_l[(16 + jm) * 40 + 39];
        } else {
            // y_{t-1}: every wave computes the SAME MFMA -> own-wave LDS copy
            f32x4 yA = {0.f, 0.f, 0.f, 0.f}, yB = {0.f, 0.f, 0.f, 0.f};
            yA = MFMA(H1A, Bo0, yA);  yB = MFMA(H1B, Bo0, yB);
            yA = MFMA(H2A, Bo1, yA);  yB = MFMA(H2B, Bo1, yB);
            if (jm < 2) {
#pragma unroll
                for (int r = 0; r < 4; ++r) {
                    y_lds[w][0][4 * q + r][jm] = yA[r];
                    y_lds[w][1][4 * q + r][jm] = yB[r];
                }
            }
            if (w == 0 && jm < 2) {   // record history (biased) for final flush
                const float bo = (jm == 0) ? bo0 : bo1;
#pragma unroll
                for (int r = 0; r < 4; ++r) {
                    y_hist[(4 * q + r) * 60 + (t - 1) * 2 + jm]      = yA[r] + bo;
                    y_hist[(16 + 4 * q + r) * 60 + (t - 1) * 2 + jm] = yB[r] + bo;
                }
            }
            asm volatile("s_waitcnt lgkmcnt(0)" ::: "memory");
            __builtin_amdgcn_sched_barrier(0);
            xA0 = y_lds[w][0][jm][0] + bo0;  xA1 = y_lds[w][0][jm][1] + bo1;
            xB0 = y_lds[w][1][jm][0] + bo0;  xB1 = y_lds[w][1][jm][1] + bo1;
        }
        const short8v AeA = embed8(xA0, xA1, wE0, wE1, bE);
        const short8v AeB = embed8(xB0, xB1, wE0, wE1, bE);

        f32x4 gA[4], gB[4];
#pragma unroll
        for (int t4 = 0; t4 < 4; ++t4) {
            f32x4 a = {bias_g[t4], bias_g[t4], bias_g[t4], bias_g[t4]};
            f32x4 b = a;
            a = MFMA(AeA, Bw[0][t4], a);  b = MFMA(AeB, Bw[0][t4], b);
            a = MFMA(H1A, Bw[1][t4], a);  b = MFMA(H1B, Bw[1][t4], b);
            a = MFMA(H2A, Bw[2][t4], a);  b = MFMA(H2B, Bw[2][t4], b);
            gA[t4] = a; gB[t4] = b;
        }
#pragma unroll
        for (int p = 0; p < 2; ++p) {
            unsigned short* nh = &hbuf[p][cur ^ 1][0];
#pragma unroll
            for (int r = 0; r < 4; ++r) {
                const f32x4* g = (p == 0) ? gA : gB;
                const float ig = sigm_s(g[0][r]);
                const float fg = sigm_s(g[1][r]);
                const float gg = tanh_s(g[2][r]);
                const float og = sigm_s(g[3][r]);
                c[p][r] = fmaf(fg, c[p][r], ig * gg);
                const float hv = og * tanh_f(c[p][r]);
                nh[(4 * q + r) * 72 + colb] = f2bf_rne(hv);
            }
        }
        __syncthreads();   // hbuf[cur^1] + y_hist visible
        cur ^= 1;
    }

    // ==================== final y (pred 29) from h_30 ====================
    {
        const short8v H1A = *(const short8v*)(&hbuf[0][cur][jm * 72 + 8 * q]);
        const short8v H2A = *(const short8v*)(&hbuf[0][cur][jm * 72 + 32 + 8 * q]);
        const short8v H1B = *(const short8v*)(&hbuf[1][cur][jm * 72 + 8 * q]);
        const short8v H2B = *(const short8v*)(&hbuf[1][cur][jm * 72 + 32 + 8 * q]);
        f32x4 yA = {0.f, 0.f, 0.f, 0.f}, yB = {0.f, 0.f, 0.f, 0.f};
        yA = MFMA(H1A, Bo0, yA);  yB = MFMA(H1B, Bo0, yB);
        yA = MFMA(H2A, Bo1, yA);  yB = MFMA(H2B, Bo1, yB);
        if (w == 0 && jm < 2) {
            const float bo = (jm == 0) ? bo0 : bo1;
#pragma unroll
            for (int r = 0; r < 4; ++r) {
                y_hist[(4 * q + r) * 60 + (PRED_LEN - 1) * 2 + jm]      = yA[r] + bo;
                y_hist[(16 + 4 * q + r) * 60 + (PRED_LEN - 1) * 2 + jm] = yB[r] + bo;
            }
        }
        __syncthreads();
        // coalesced flush: 32 rows x 60 f32 = 1920 contiguous floats
        float* op = out + (size_t)bb * 60;
        for (int k2 = id; k2 < 1920; k2 += 256) op[k2] = y_hist[k2];
    }
}

extern "C" void kernel_launch(void* const* d_in, const int* in_sizes, int n_in,
                              void* d_out, int out_size, void* d_ws, size_t ws_size,
                              hipStream_t stream) {
    (void)in_sizes; (void)n_in; (void)d_ws; (void)ws_size; (void)out_size;
    const float* obs    = (const float*)d_in[0];
    const float* noise  = (const float*)d_in[1];
    const float* scene  = (const float*)d_in[2];
    const float* W_emb  = (const float*)d_in[3];
    const float* b_emb  = (const float*)d_in[4];
    const float* Wih_e  = (const float*)d_in[5];
    const float* Whh_e  = (const float*)d_in[6];
    const float* b_e    = (const float*)d_in[7];
    const float* W_h    = (const float*)d_in[8];
    const float* b_h    = (const float*)d_in[9];
    const float* W_c    = (const float*)d_in[10];
    const float* b_c    = (const float*)d_in[11];
    const float* Wih_d  = (const float*)d_in[12];
    const float* Whh_d  = (const float*)d_in[13];
    const float* b_d    = (const float*)d_in[14];
    const float* W_out  = (const float*)d_in[15];
    const float* b_out  = (const float*)d_in[16];
    float* out = (float*)d_out;

    dim3 grid(65536 / 32), block(256);
    hipLaunchKernelGGL(traj_mfma, grid, block, 0, stream,
                       obs, noise, scene, W_emb, b_emb,
                       Wih_e, Whh_e, b_e, W_h, b_h, W_c, b_c,
                       Wih_d, Whh_d, b_d, W_out, b_out, out);
}

// Round 13
// 349.099 us; speedup vs baseline: 1.2924x; 1.0424x over previous
//
#include <hip/hip_runtime.h>
#include <cstddef>

#define OBS_LEN  20
#define PRED_LEN 30

typedef __attribute__((ext_vector_type(8))) short short8v;  // 8 bf16 (4 VGPRs)
typedef __attribute__((ext_vector_type(4))) float f32x4;

// branchless RNE f32->bf16 (no libcall) — cold paths only
__device__ __forceinline__ unsigned short f2bf_rne(float x) {
    const unsigned u = __builtin_bit_cast(unsigned, x);
    return (unsigned short)((u + 0x7FFFu + ((u >> 16) & 1u)) >> 16);
}
// packed f32x2 -> bf16x2 in ONE VALU inst (RNE on gfx950)
__device__ __forceinline__ unsigned cvt_pk_bf16(float lo, float hi) {
    unsigned d;
    asm("v_cvt_pk_bf16_f32 %0, %1, %2" : "=v"(d) : "v"(lo), "v"(hi));
    return d;
}
// sigmoid from PRESCALED acc: y = -log2e * x  ->  sigma(x) = rcp(1+exp2(y))
__device__ __forceinline__ float sigm_s(float y) {
    return __builtin_amdgcn_rcpf(1.0f + __builtin_amdgcn_exp2f(y));
}
// tanh from PRESCALED acc: y = -2*log2e * x -> tanh(x) = 2*rcp(1+exp2(y)) - 1
__device__ __forceinline__ float tanh_s(float y) {
    return fmaf(2.0f, __builtin_amdgcn_rcpf(1.0f + __builtin_amdgcn_exp2f(y)), -1.0f);
}
// tanh of an UNSCALED value (for tanh(c))
__device__ __forceinline__ float tanh_f(float x) {
    return tanh_s(x * -2.885390082f);
}
// weight-row load -> bf16x8 fragment, scaled by s before conversion (cold)
__device__ __forceinline__ short8v ldw8s(const float* __restrict__ p, float s) {
    const float4 a = *(const float4*)(p);
    const float4 b = *(const float4*)(p + 4);
    uint4 w;
    w.x = (unsigned)f2bf_rne(a.x * s) | ((unsigned)f2bf_rne(a.y * s) << 16);
    w.y = (unsigned)f2bf_rne(a.z * s) | ((unsigned)f2bf_rne(a.w * s) << 16);
    w.z = (unsigned)f2bf_rne(b.x * s) | ((unsigned)f2bf_rne(b.y * s) << 16);
    w.w = (unsigned)f2bf_rne(b.z * s) | ((unsigned)f2bf_rne(b.w * s) << 16);
    return __builtin_bit_cast(short8v, w);
}
__device__ __forceinline__ short8v ldw8(const float* __restrict__ p) {
    return ldw8s(p, 1.0f);
}
// per-lane embed: 8 units (rows 8q..8q+7) -> A-fragment, cvt_pk packing
__device__ __forceinline__ short8v embed8(float x0, float x1,
        const float wE0[8], const float wE1[8], const float bE[8]) {
    float e[8];
#pragma unroll
    for (int j = 0; j < 8; ++j)
        e[j] = fmaxf(0.f, fmaf(wE0[j], x0, fmaf(wE1[j], x1, bE[j])));
    uint4 w;
    w.x = cvt_pk_bf16(e[0], e[1]);
    w.y = cvt_pk_bf16(e[2], e[3]);
    w.z = cvt_pk_bf16(e[4], e[5]);
    w.w = cvt_pk_bf16(e[6], e[7]);
    return __builtin_bit_cast(short8v, w);
}

#define MFMA(A, B, C) __builtin_amdgcn_mfma_f32_16x16x32_bf16((A), (B), (C), 0, 0, 0)

// gate prescales: i,f,o -> -log2e ; g -> -2log2e
#define GS0 -1.442695041f
#define GS2 -2.885390082f

__device__ __forceinline__ void load_gates(short8v Bw[3][4], float bias_g[4],
        const float* __restrict__ Wih, const float* __restrict__ Whh,
        const float* __restrict__ bias, int colb, int q) {
    const float GS[4] = {GS0, GS0, GS2, GS0};
#pragma unroll
    for (int t = 0; t < 4; ++t) {
        const int row = t * 64 + colb;
        const float s = GS[t];
        Bw[0][t] = ldw8s(Wih + row * 32 + 8 * q, s);
        Bw[1][t] = ldw8s(Whh + row * 64 + 8 * q, s);
        Bw[2][t] = ldw8s(Whh + row * 64 + 32 + 8 * q, s);
        bias_g[t] = bias[row] * s;
    }
}

// R12 post-mortem: issue-bound (VALU-busy ~1550cy/wave-step, trans-heavy).
// R13: instruction diet + dependency reorder.
//  (1) v_cvt_pk_bf16_f32 replaces scalar RNE in embed + h-store (-70 inst/step)
//  (2) decoder: y-MFMA issued FIRST, then 16 H-gate MFMAs, THEN y store/wait/
//      read + embed + Ae-MFMAs -> y latency + serial feedback chain hide
//      under the gate MFMAs.
extern "C" __global__ void __launch_bounds__(256, 2)
traj_mfma(const float* __restrict__ obs,   const float* __restrict__ noise,
          const float* __restrict__ scene,
          const float* __restrict__ W_emb, const float* __restrict__ b_emb,
          const float* __restrict__ Wih_e, const float* __restrict__ Whh_e, const float* __restrict__ b_e,
          const float* __restrict__ W_h,   const float* __restrict__ b_h,
          const float* __restrict__ W_c,   const float* __restrict__ b_c,
          const float* __restrict__ Wih_d, const float* __restrict__ Whh_d, const float* __restrict__ b_d,
          const float* __restrict__ W_out, const float* __restrict__ b_out,
          float* __restrict__ out)
{
    __shared__ __align__(16) unsigned short hbuf[2][2][1152]; // [tile][buf] 16x72 bf16
    __shared__ __align__(16) float uni[2816];                 // obs_l | ns | y_hist union
    __shared__ __align__(16) float y_lds[4][2][16][2];        // per-WAVE y copy

    const int id = threadIdx.x;
    const int l    = id & 63;
    const int w    = id >> 6;        // wave = gate-column slice
    const int q    = l >> 4;
    const int jm   = l & 15;
    const int colb = w * 16 + jm;    // hidden j in [0,64)
    const int bb   = blockIdx.x * 32;

    float* obs_l = uni;                                   // 1280 f32
    unsigned short* ns = (unsigned short*)(uni + 1280);   // 3072 bf16
    float* y_hist = uni;                                  // 1920 f32 (aliases)

    // ---------------- overlay gate-weight registers (one phase at a time) ----
    short8v Bw[3][4];
    float bias_g[4];
    load_gates(Bw, bias_g, Wih_e, Whh_e, b_e, colb, q);   // encoder set

    // per-lane embed weights: units 8q..8q+7
    float wE0[8], wE1[8], bE[8];
#pragma unroll
    for (int j = 0; j < 8; ++j) {
        wE0[j] = W_emb[(8 * q + j) * 2];
        wE1[j] = W_emb[(8 * q + j) * 2 + 1];
        bE[j]  = b_emb[8 * q + j];
    }
    const float bo0 = b_out[0], bo1 = b_out[1];

    // init h=0, stage obs (32 rows)
    {
        unsigned* hz = (unsigned*)&hbuf[0][0][0];
        for (int k2 = id; k2 < 2304; k2 += 256) hz[k2] = 0u;
        for (int k2 = id; k2 < 1280; k2 += 256) obs_l[k2] = obs[(size_t)bb * 40 + k2];
    }
    float c[2][4];
#pragma unroll
    for (int p = 0; p < 2; ++p)
#pragma unroll
        for (int r = 0; r < 4; ++r) c[p][r] = 0.f;
    __syncthreads();

    int cur = 0;

    // packed h-store: 4 rows (stride 72 shorts = 144B), 2 cvt_pk + 4 b16 stores
#define H_STORE4(nh_, hv0, hv1, hv2, hv3)                         \
    {                                                             \
        const unsigned p01 = cvt_pk_bf16((hv0), (hv1));           \
        const unsigned p23 = cvt_pk_bf16((hv2), (hv3));           \
        unsigned short* b_ = (nh_) + (4 * q) * 72 + colb;         \
        b_[0]       = (unsigned short)p01;                        \
        b_[72]      = (unsigned short)(p01 >> 16);                \
        b_[144]     = (unsigned short)p23;                        \
        b_[216]     = (unsigned short)(p23 >> 16);                \
    }

    // ==================== encoder (1 barrier/step) ====================
#pragma unroll 1
    for (int t = 0; t < OBS_LEN; ++t) {
        const short8v H1A = *(const short8v*)(&hbuf[0][cur][jm * 72 + 8 * q]);
        const short8v H2A = *(const short8v*)(&hbuf[0][cur][jm * 72 + 32 + 8 * q]);
        const short8v H1B = *(const short8v*)(&hbuf[1][cur][jm * 72 + 8 * q]);
        const short8v H2B = *(const short8v*)(&hbuf[1][cur][jm * 72 + 32 + 8 * q]);

        // H-gate MFMAs first; embed overlaps their latency
        f32x4 gA[4], gB[4];
#pragma unroll
        for (int t4 = 0; t4 < 4; ++t4) {
            f32x4 a = {bias_g[t4], bias_g[t4], bias_g[t4], bias_g[t4]};
            f32x4 b = a;
            a = MFMA(H1A, Bw[1][t4], a);  b = MFMA(H1B, Bw[1][t4], b);
            a = MFMA(H2A, Bw[2][t4], a);  b = MFMA(H2B, Bw[2][t4], b);
            gA[t4] = a; gB[t4] = b;
        }
        const short8v AeA = embed8(obs_l[jm * 40 + 2 * t], obs_l[jm * 40 + 2 * t + 1],
                                   wE0, wE1, bE);
        const short8v AeB = embed8(obs_l[(16 + jm) * 40 + 2 * t], obs_l[(16 + jm) * 40 + 2 * t + 1],
                                   wE0, wE1, bE);
#pragma unroll
        for (int t4 = 0; t4 < 4; ++t4) {
            gA[t4] = MFMA(AeA, Bw[0][t4], gA[t4]);
            gB[t4] = MFMA(AeB, Bw[0][t4], gB[t4]);
        }
#pragma unroll
        for (int p = 0; p < 2; ++p) {
            unsigned short* nh = &hbuf[p][cur ^ 1][0];
            float hv[4];
#pragma unroll
            for (int r = 0; r < 4; ++r) {
                const f32x4* g = (p == 0) ? gA : gB;
                const float ig = sigm_s(g[0][r]);
                const float fg = sigm_s(g[1][r]);
                const float gg = tanh_s(g[2][r]);
                const float og = sigm_s(g[3][r]);
                c[p][r] = fmaf(fg, c[p][r], ig * gg);
                hv[r] = og * tanh_f(c[p][r]);
            }
            H_STORE4(nh, hv[0], hv[1], hv[2], hv[3]);
        }
        __syncthreads();
        cur ^= 1;
    }

    // -------- swap overlay to decoder weights (hidden under cond MFMAs) -----
    load_gates(Bw, bias_g, Wih_d, Whh_d, b_d, colb, q);
    short8v Bo0, Bo1;
    {
        const short8v z = {0, 0, 0, 0, 0, 0, 0, 0};
        if (jm < 2) {
            Bo0 = ldw8(W_out + jm * 64 + 8 * q);
            Bo1 = ldw8(W_out + jm * 64 + 32 + 8 * q);
        } else { Bo0 = z; Bo1 = z; }
    }

    // ==================== cond -> decoder init ====================
    {
        {   // stage [noise | scene | 0] as bf16 into ns (union region)
            const int i2 = id >> 4, cb = (id & 15) * 6;
#pragma unroll
            for (int p = 0; p < 2; ++p) {
                const int row = bb + p * 16 + i2;
#pragma unroll
                for (int cc = 0; cc < 6; ++cc) {
                    const int col = cb + cc;
                    float v;
                    if (col < 16)      v = noise[(size_t)row * 16 + col];
                    else if (col < 80) v = scene[(size_t)row * 64 + (col - 16)];
                    else               v = 0.f;
                    ns[p * 1536 + i2 * 96 + col] = f2bf_rne(v);
                }
            }
        }
        __syncthreads();

        const short8v A0A = *(const short8v*)(&hbuf[0][cur][jm * 72 + 8 * q]);
        const short8v A1A = *(const short8v*)(&hbuf[0][cur][jm * 72 + 32 + 8 * q]);
        const short8v A0B = *(const short8v*)(&hbuf[1][cur][jm * 72 + 8 * q]);
        const short8v A1B = *(const short8v*)(&hbuf[1][cur][jm * 72 + 32 + 8 * q]);
        const short8v N0A = *(const short8v*)(ns + jm * 96 + 8 * q);
        const short8v N1A = *(const short8v*)(ns + jm * 96 + 32 + 8 * q);
        const short8v N2A = *(const short8v*)(ns + jm * 96 + 64 + 8 * q);
        const short8v N0B = *(const short8v*)(ns + 1536 + jm * 96 + 8 * q);
        const short8v N1B = *(const short8v*)(ns + 1536 + jm * 96 + 32 + 8 * q);
        const short8v N2B = *(const short8v*)(ns + 1536 + jm * 96 + 64 + 8 * q);
        const short8v zfrag = {0, 0, 0, 0, 0, 0, 0, 0};

        {   // h0
            short8v Bf[5];
#pragma unroll
            for (int kt = 0; kt < 4; ++kt)
                Bf[kt] = ldw8(W_h + (size_t)colb * 144 + kt * 32 + 8 * q);
            Bf[4] = (q < 2) ? ldw8(W_h + (size_t)colb * 144 + 128 + 8 * q) : zfrag;
            f32x4 ahA = {b_h[colb], b_h[colb], b_h[colb], b_h[colb]};
            f32x4 ahB = ahA;
            ahA = MFMA(A0A, Bf[0], ahA);  ahB = MFMA(A0B, Bf[0], ahB);
            ahA = MFMA(A1A, Bf[1], ahA);  ahB = MFMA(A1B, Bf[1], ahB);
            ahA = MFMA(N0A, Bf[2], ahA);  ahB = MFMA(N0B, Bf[2], ahB);
            ahA = MFMA(N1A, Bf[3], ahA);  ahB = MFMA(N1B, Bf[3], ahB);
            ahA = MFMA(N2A, Bf[4], ahA);  ahB = MFMA(N2B, Bf[4], ahB);
            unsigned short* nh0 = &hbuf[0][cur ^ 1][0];
            unsigned short* nh1 = &hbuf[1][cur ^ 1][0];
            H_STORE4(nh0, ahA[0], ahA[1], ahA[2], ahA[3]);
            H_STORE4(nh1, ahB[0], ahB[1], ahB[2], ahB[3]);
        }
        {   // c0
            short8v Bf[5];
#pragma unroll
            for (int kt = 0; kt < 4; ++kt)
                Bf[kt] = ldw8(W_c + (size_t)colb * 144 + kt * 32 + 8 * q);
            Bf[4] = (q < 2) ? ldw8(W_c + (size_t)colb * 144 + 128 + 8 * q) : zfrag;
            f32x4 acA = {b_c[colb], b_c[colb], b_c[colb], b_c[colb]};
            f32x4 acB = acA;
            acA = MFMA(A0A, Bf[0], acA);  acB = MFMA(A0B, Bf[0], acB);
            acA = MFMA(A1A, Bf[1], acA);  acB = MFMA(A1B, Bf[1], acB);
            acA = MFMA(N0A, Bf[2], acA);  acB = MFMA(N0B, Bf[2], acB);
            acA = MFMA(N1A, Bf[3], acA);  acB = MFMA(N1B, Bf[3], acB);
            acA = MFMA(N2A, Bf[4], acA);  acB = MFMA(N2B, Bf[4], acB);
#pragma unroll
            for (int r = 0; r < 4; ++r) { c[0][r] = acA[r]; c[1][r] = acB[r]; }
        }
        __syncthreads();
        cur ^= 1;
    }

    // ==================== decoder (1 barrier/step) ====================
#pragma unroll 1
    for (int t = 0; t < PRED_LEN; ++t) {
        const short8v H1A = *(const short8v*)(&hbuf[0][cur][jm * 72 + 8 * q]);
        const short8v H2A = *(const short8v*)(&hbuf[0][cur][jm * 72 + 32 + 8 * q]);
        const short8v H1B = *(const short8v*)(&hbuf[1][cur][jm * 72 + 8 * q]);
        const short8v H2B = *(const short8v*)(&hbuf[1][cur][jm * 72 + 32 + 8 * q]);

        f32x4 gA[4], gB[4];
        float xA0, xA1, xB0, xB1;
        if (t == 0) {
            // H-gate MFMAs first, embed under them
#pragma unroll
            for (int t4 = 0; t4 < 4; ++t4) {
                f32x4 a = {bias_g[t4], bias_g[t4], bias_g[t4], bias_g[t4]};
                f32x4 b = a;
                a = MFMA(H1A, Bw[1][t4], a);  b = MFMA(H1B, Bw[1][t4], b);
                a = MFMA(H2A, Bw[2][t4], a);  b = MFMA(H2B, Bw[2][t4], b);
                gA[t4] = a; gB[t4] = b;
            }
            xA0 = obs_l[jm * 40 + 38];        xA1 = obs_l[jm * 40 + 39];
            xB0 = obs_l[(16 + jm) * 40 + 38]; xB1 = obs_l[(16 + jm) * 40 + 39];
        } else {
            // (1) y-MFMA issued FIRST
            f32x4 yA = {0.f, 0.f, 0.f, 0.f}, yB = {0.f, 0.f, 0.f, 0.f};
            yA = MFMA(H1A, Bo0, yA);  yB = MFMA(H1B, Bo0, yB);
            yA = MFMA(H2A, Bo1, yA);  yB = MFMA(H2B, Bo1, yB);
            // (2) 16 independent H-gate MFMAs cover the y-MFMA latency
#pragma unroll
            for (int t4 = 0; t4 < 4; ++t4) {
                f32x4 a = {bias_g[t4], bias_g[t4], bias_g[t4], bias_g[t4]};
                f32x4 b = a;
                a = MFMA(H1A, Bw[1][t4], a);  b = MFMA(H1B, Bw[1][t4], b);
                a = MFMA(H2A, Bw[2][t4], a);  b = MFMA(H2B, Bw[2][t4], b);
                gA[t4] = a; gB[t4] = b;
            }
            // (3) y_lds stores land after y-MFMA completes (hidden above)
            if (jm < 2) {
#pragma unroll
                for (int r = 0; r < 4; ++r) {
                    y_lds[w][0][4 * q + r][jm] = yA[r];
                    y_lds[w][1][4 * q + r][jm] = yB[r];
                }
            }
            if (w == 0 && jm < 2) {
                const float bo = (jm == 0) ? bo0 : bo1;
#pragma unroll
                for (int r = 0; r < 4; ++r) {
                    y_hist[(4 * q + r) * 60 + (t - 1) * 2 + jm]      = yA[r] + bo;
                    y_hist[(16 + 4 * q + r) * 60 + (t - 1) * 2 + jm] = yB[r] + bo;
                }
            }
            asm volatile("s_waitcnt lgkmcnt(0)" ::: "memory");
            __builtin_amdgcn_sched_barrier(0);
            xA0 = y_lds[w][0][jm][0] + bo0;  xA1 = y_lds[w][0][jm][1] + bo1;
            xB0 = y_lds[w][1][jm][0] + bo0;  xB1 = y_lds[w][1][jm][1] + bo1;
        }
        const short8v AeA = embed8(xA0, xA1, wE0, wE1, bE);
        const short8v AeB = embed8(xB0, xB1, wE0, wE1, bE);
#pragma unroll
        for (int t4 = 0; t4 < 4; ++t4) {
            gA[t4] = MFMA(AeA, Bw[0][t4], gA[t4]);
            gB[t4] = MFMA(AeB, Bw[0][t4], gB[t4]);
        }
#pragma unroll
        for (int p = 0; p < 2; ++p) {
            unsigned short* nh = &hbuf[p][cur ^ 1][0];
            float hv[4];
#pragma unroll
            for (int r = 0; r < 4; ++r) {
                const f32x4* g = (p == 0) ? gA : gB;
                const float ig = sigm_s(g[0][r]);
                const float fg = sigm_s(g[1][r]);
                const float gg = tanh_s(g[2][r]);
                const float og = sigm_s(g[3][r]);
                c[p][r] = fmaf(fg, c[p][r], ig * gg);
                hv[r] = og * tanh_f(c[p][r]);
            }
            H_STORE4(nh, hv[0], hv[1], hv[2], hv[3]);
        }
        __syncthreads();   // hbuf[cur^1] + y_hist visible
        cur ^= 1;
    }

    // ==================== final y (pred 29) from h_30 ====================
    {
        const short8v H1A = *(const short8v*)(&hbuf[0][cur][jm * 72 + 8 * q]);
        const short8v H2A = *(const short8v*)(&hbuf[0][cur][jm * 72 + 32 + 8 * q]);
        const short8v H1B = *(const short8v*)(&hbuf[1][cur][jm * 72 + 8 * q]);
        const short8v H2B = *(const short8v*)(&hbuf[1][cur][jm * 72 + 32 + 8 * q]);
        f32x4 yA = {0.f, 0.f, 0.f, 0.f}, yB = {0.f, 0.f, 0.f, 0.f};
        yA = MFMA(H1A, Bo0, yA);  yB = MFMA(H1B, Bo0, yB);
        yA = MFMA(H2A, Bo1, yA);  yB = MFMA(H2B, Bo1, yB);
        if (w == 0 && jm < 2) {
            const float bo = (jm == 0) ? bo0 : bo1;
#pragma unroll
            for (int r = 0; r < 4; ++r) {
                y_hist[(4 * q + r) * 60 + (PRED_LEN - 1) * 2 + jm]      = yA[r] + bo;
                y_hist[(16 + 4 * q + r) * 60 + (PRED_LEN - 1) * 2 + jm] = yB[r] + bo;
            }
        }
        __syncthreads();
        float* op = out + (size_t)bb * 60;
        for (int k2 = id; k2 < 1920; k2 += 256) op[k2] = y_hist[k2];
    }
#undef H_STORE4
}

extern "C" void kernel_launch(void* const* d_in, const int* in_sizes, int n_in,
                              void* d_out, int out_size, void* d_ws, size_t ws_size,
                              hipStream_t stream) {
    (void)in_sizes; (void)n_in; (void)d_ws; (void)ws_size; (void)out_size;
    const float* obs    = (const float*)d_in[0];
    const float* noise  = (const float*)d_in[1];
    const float* scene  = (const float*)d_in[2];
    const float* W_emb  = (const float*)d_in[3];
    const float* b_emb  = (const float*)d_in[4];
    const float* Wih_e  = (const float*)d_in[5];
    const float* Whh_e  = (const float*)d_in[6];
    const float* b_e    = (const float*)d_in[7];
    const float* W_h    = (const float*)d_in[8];
    const float* b_h    = (const float*)d_in[9];
    const float* W_c    = (const float*)d_in[10];
    const float* b_c    = (const float*)d_in[11];
    const float* Wih_d  = (const float*)d_in[12];
    const float* Whh_d  = (const float*)d_in[13];
    const float* b_d    = (const float*)d_in[14];
    const float* W_out  = (const float*)d_in[15];
    const float* b_out  = (const float*)d_in[16];
    float* out = (float*)d_out;

    dim3 grid(65536 / 32), block(256);
    hipLaunchKernelGGL(traj_mfma, grid, block, 0, stream,
                       obs, noise, scene, W_emb, b_emb,
                       Wih_e, Whh_e, b_e, W_h, b_h, W_c, b_c,
                       Wih_d, Whh_d, b_d, W_out, b_out, out);
}

// Round 14
// 329.888 us; speedup vs baseline: 1.3677x; 1.0582x over previous
//
#include <hip/hip_runtime.h>
#include <cstddef>

#define OBS_LEN  20
#define PRED_LEN 30

typedef __attribute__((ext_vector_type(8))) short short8v;  // 8 bf16 (4 VGPRs)
typedef __attribute__((ext_vector_type(4))) float f32x4;

// branchless RNE f32->bf16 (no libcall) — cold paths only
__device__ __forceinline__ unsigned short f2bf_rne(float x) {
    const unsigned u = __builtin_bit_cast(unsigned, x);
    return (unsigned short)((u + 0x7FFFu + ((u >> 16) & 1u)) >> 16);
}
// packed f32x2 -> bf16x2 in ONE VALU inst (RNE on gfx950)
__device__ __forceinline__ unsigned cvt_pk_bf16(float lo, float hi) {
    unsigned d;
    asm("v_cvt_pk_bf16_f32 %0, %1, %2" : "=v"(d) : "v"(lo), "v"(hi));
    return d;
}

// gate prescales: i,f,o -> -log2e ; g -> -2log2e (folded into weights)
#define GS0 -1.442695041f
#define GS2 -2.885390082f

// Fused-rcp LSTM nonlinearity: 8 trans (5 exp2 + 3 rcp) per output vs 10.
//   i*g       = (1-Eg) * rcp((1+Ei)(1+Eg))
//   o*tanh(c) = (1-Ec) * rcp((1+Eo)(1+Ec))
// fmin(y,126) on numerator exps keeps inf/NaN out; denominator infs
// degrade to the correct limit (rcp(inf)=0).
__device__ __forceinline__ float lstm_h(float yi, float yf, float yg, float yo,
                                        float& c) {
    const float Ei = __builtin_amdgcn_exp2f(yi);
    const float Ef = __builtin_amdgcn_exp2f(yf);
    const float Eg = __builtin_amdgcn_exp2f(fminf(yg, 126.0f));
    const float Eo = __builtin_amdgcn_exp2f(yo);
    const float fg = __builtin_amdgcn_rcpf(1.0f + Ef);
    const float ig = (1.0f - Eg) *
                     __builtin_amdgcn_rcpf((1.0f + Ei) * (1.0f + Eg));
    const float cn = fmaf(fg, c, ig);
    c = cn;
    const float Ec = __builtin_amdgcn_exp2f(fminf(cn * GS2, 126.0f));
    return (1.0f - Ec) * __builtin_amdgcn_rcpf((1.0f + Eo) * (1.0f + Ec));
}

// weight-row load -> bf16x8 fragment, scaled by s before conversion (cold)
__device__ __forceinline__ short8v ldw8s(const float* __restrict__ p, float s) {
    const float4 a = *(const float4*)(p);
    const float4 b = *(const float4*)(p + 4);
    uint4 w;
    w.x = (unsigned)f2bf_rne(a.x * s) | ((unsigned)f2bf_rne(a.y * s) << 16);
    w.y = (unsigned)f2bf_rne(a.z * s) | ((unsigned)f2bf_rne(a.w * s) << 16);
    w.z = (unsigned)f2bf_rne(b.x * s) | ((unsigned)f2bf_rne(b.y * s) << 16);
    w.w = (unsigned)f2bf_rne(b.z * s) | ((unsigned)f2bf_rne(b.w * s) << 16);
    return __builtin_bit_cast(short8v, w);
}
__device__ __forceinline__ short8v ldw8(const float* __restrict__ p) {
    return ldw8s(p, 1.0f);
}
// per-lane embed: 8 units (rows 8q..8q+7) -> A-fragment, cvt_pk packing
__device__ __forceinline__ short8v embed8(float x0, float x1,
        const float wE0[8], const float wE1[8], const float bE[8]) {
    float e[8];
#pragma unroll
    for (int j = 0; j < 8; ++j)
        e[j] = fmaxf(0.f, fmaf(wE0[j], x0, fmaf(wE1[j], x1, bE[j])));
    uint4 w;
    w.x = cvt_pk_bf16(e[0], e[1]);
    w.y = cvt_pk_bf16(e[2], e[3]);
    w.z = cvt_pk_bf16(e[4], e[5]);
    w.w = cvt_pk_bf16(e[6], e[7]);
    return __builtin_bit_cast(short8v, w);
}

#define MFMA(A, B, C) __builtin_amdgcn_mfma_f32_16x16x32_bf16((A), (B), (C), 0, 0, 0)

__device__ __forceinline__ void load_gates(short8v Bw[3][4], float bias_g[4],
        const float* __restrict__ Wih, const float* __restrict__ Whh,
        const float* __restrict__ bias, int colb, int q) {
    const float GS[4] = {GS0, GS0, GS2, GS0};
#pragma unroll
    for (int t = 0; t < 4; ++t) {
        const int row = t * 64 + colb;
        const float s = GS[t];
        Bw[0][t] = ldw8s(Wih + row * 32 + 8 * q, s);
        Bw[1][t] = ldw8s(Whh + row * 64 + 8 * q, s);
        Bw[2][t] = ldw8s(Whh + row * 64 + 32 + 8 * q, s);
        bias_g[t] = bias[row] * s;
    }
}

// R13 post-mortem: occupancy pinned at 2 waves/SIMD by UNIFIED VGPR+AGPR
// (~128 arch + ~40 acc = ~170/wave; VGPR_Count excludes AGPR). 512/3 = 170
// is exactly the 3-wave boundary -> launch_bounds(256,3) asks the allocator
// to fit it. Plus fused-rcp nonlinearity: 8 trans/output instead of 10.
extern "C" __global__ void __launch_bounds__(256, 3)
traj_mfma(const float* __restrict__ obs,   const float* __restrict__ noise,
          const float* __restrict__ scene,
          const float* __restrict__ W_emb, const float* __restrict__ b_emb,
          const float* __restrict__ Wih_e, const float* __restrict__ Whh_e, const float* __restrict__ b_e,
          const float* __restrict__ W_h,   const float* __restrict__ b_h,
          const float* __restrict__ W_c,   const float* __restrict__ b_c,
          const float* __restrict__ Wih_d, const float* __restrict__ Whh_d, const float* __restrict__ b_d,
          const float* __restrict__ W_out, const float* __restrict__ b_out,
          float* __restrict__ out)
{
    __shared__ __align__(16) unsigned short hbuf[2][2][1152]; // [tile][buf] 16x72 bf16
    __shared__ __align__(16) float uni[2816];                 // obs_l | ns | y_hist union
    __shared__ __align__(16) float y_lds[4][2][16][2];        // per-WAVE y copy

    const int id = threadIdx.x;
    const int l    = id & 63;
    const int w    = id >> 6;        // wave = gate-column slice
    const int q    = l >> 4;
    const int jm   = l & 15;
    const int colb = w * 16 + jm;    // hidden j in [0,64)
    const int bb   = blockIdx.x * 32;

    float* obs_l = uni;                                   // 1280 f32
    unsigned short* ns = (unsigned short*)(uni + 1280);   // 3072 bf16
    float* y_hist = uni;                                  // 1920 f32 (aliases)

    // ---------------- overlay gate-weight registers (one phase at a time) ----
    short8v Bw[3][4];
    float bias_g[4];
    load_gates(Bw, bias_g, Wih_e, Whh_e, b_e, colb, q);   // encoder set

    // per-lane embed weights: units 8q..8q+7
    float wE0[8], wE1[8], bE[8];
#pragma unroll
    for (int j = 0; j < 8; ++j) {
        wE0[j] = W_emb[(8 * q + j) * 2];
        wE1[j] = W_emb[(8 * q + j) * 2 + 1];
        bE[j]  = b_emb[8 * q + j];
    }
    const float bo0 = b_out[0], bo1 = b_out[1];

    // init h=0, stage obs (32 rows)
    {
        unsigned* hz = (unsigned*)&hbuf[0][0][0];
        for (int k2 = id; k2 < 2304; k2 += 256) hz[k2] = 0u;
        for (int k2 = id; k2 < 1280; k2 += 256) obs_l[k2] = obs[(size_t)bb * 40 + k2];
    }
    float c[2][4];
#pragma unroll
    for (int p = 0; p < 2; ++p)
#pragma unroll
        for (int r = 0; r < 4; ++r) c[p][r] = 0.f;
    __syncthreads();

    int cur = 0;

    // packed h-store: 4 rows (stride 72 shorts = 144B), 2 cvt_pk + 4 b16 stores
#define H_STORE4(nh_, hv0, hv1, hv2, hv3)                         \
    {                                                             \
        const unsigned p01 = cvt_pk_bf16((hv0), (hv1));           \
        const unsigned p23 = cvt_pk_bf16((hv2), (hv3));           \
        unsigned short* b_ = (nh_) + (4 * q) * 72 + colb;         \
        b_[0]       = (unsigned short)p01;                        \
        b_[72]      = (unsigned short)(p01 >> 16);                \
        b_[144]     = (unsigned short)p23;                        \
        b_[216]     = (unsigned short)(p23 >> 16);                \
    }

    // ==================== encoder (1 barrier/step) ====================
#pragma unroll 1
    for (int t = 0; t < OBS_LEN; ++t) {
        const short8v H1A = *(const short8v*)(&hbuf[0][cur][jm * 72 + 8 * q]);
        const short8v H2A = *(const short8v*)(&hbuf[0][cur][jm * 72 + 32 + 8 * q]);
        const short8v H1B = *(const short8v*)(&hbuf[1][cur][jm * 72 + 8 * q]);
        const short8v H2B = *(const short8v*)(&hbuf[1][cur][jm * 72 + 32 + 8 * q]);

        // H-gate MFMAs first; embed overlaps their latency
        f32x4 gA[4], gB[4];
#pragma unroll
        for (int t4 = 0; t4 < 4; ++t4) {
            f32x4 a = {bias_g[t4], bias_g[t4], bias_g[t4], bias_g[t4]};
            f32x4 b = a;
            a = MFMA(H1A, Bw[1][t4], a);  b = MFMA(H1B, Bw[1][t4], b);
            a = MFMA(H2A, Bw[2][t4], a);  b = MFMA(H2B, Bw[2][t4], b);
            gA[t4] = a; gB[t4] = b;
        }
        const short8v AeA = embed8(obs_l[jm * 40 + 2 * t], obs_l[jm * 40 + 2 * t + 1],
                                   wE0, wE1, bE);
        const short8v AeB = embed8(obs_l[(16 + jm) * 40 + 2 * t], obs_l[(16 + jm) * 40 + 2 * t + 1],
                                   wE0, wE1, bE);
#pragma unroll
        for (int t4 = 0; t4 < 4; ++t4) {
            gA[t4] = MFMA(AeA, Bw[0][t4], gA[t4]);
            gB[t4] = MFMA(AeB, Bw[0][t4], gB[t4]);
        }
#pragma unroll
        for (int p = 0; p < 2; ++p) {
            unsigned short* nh = &hbuf[p][cur ^ 1][0];
            float hv[4];
#pragma unroll
            for (int r = 0; r < 4; ++r) {
                const f32x4* g = (p == 0) ? gA : gB;
                hv[r] = lstm_h(g[0][r], g[1][r], g[2][r], g[3][r], c[p][r]);
            }
            H_STORE4(nh, hv[0], hv[1], hv[2], hv[3]);
        }
        __syncthreads();
        cur ^= 1;
    }

    // -------- swap overlay to decoder weights (hidden under cond MFMAs) -----
    load_gates(Bw, bias_g, Wih_d, Whh_d, b_d, colb, q);
    short8v Bo0, Bo1;
    {
        const short8v z = {0, 0, 0, 0, 0, 0, 0, 0};
        if (jm < 2) {
            Bo0 = ldw8(W_out + jm * 64 + 8 * q);
            Bo1 = ldw8(W_out + jm * 64 + 32 + 8 * q);
        } else { Bo0 = z; Bo1 = z; }
    }

    // ==================== cond -> decoder init ====================
    {
        {   // stage [noise | scene | 0] as bf16 into ns (union region)
            const int i2 = id >> 4, cb = (id & 15) * 6;
#pragma unroll
            for (int p = 0; p < 2; ++p) {
                const int row = bb + p * 16 + i2;
#pragma unroll
                for (int cc = 0; cc < 6; ++cc) {
                    const int col = cb + cc;
                    float v;
                    if (col < 16)      v = noise[(size_t)row * 16 + col];
                    else if (col < 80) v = scene[(size_t)row * 64 + (col - 16)];
                    else               v = 0.f;
                    ns[p * 1536 + i2 * 96 + col] = f2bf_rne(v);
                }
            }
        }
        __syncthreads();

        const short8v A0A = *(const short8v*)(&hbuf[0][cur][jm * 72 + 8 * q]);
        const short8v A1A = *(const short8v*)(&hbuf[0][cur][jm * 72 + 32 + 8 * q]);
        const short8v A0B = *(const short8v*)(&hbuf[1][cur][jm * 72 + 8 * q]);
        const short8v A1B = *(const short8v*)(&hbuf[1][cur][jm * 72 + 32 + 8 * q]);
        const short8v N0A = *(const short8v*)(ns + jm * 96 + 8 * q);
        const short8v N1A = *(const short8v*)(ns + jm * 96 + 32 + 8 * q);
        const short8v N2A = *(const short8v*)(ns + jm * 96 + 64 + 8 * q);
        const short8v N0B = *(const short8v*)(ns + 1536 + jm * 96 + 8 * q);
        const short8v N1B = *(const short8v*)(ns + 1536 + jm * 96 + 32 + 8 * q);
        const short8v N2B = *(const short8v*)(ns + 1536 + jm * 96 + 64 + 8 * q);
        const short8v zfrag = {0, 0, 0, 0, 0, 0, 0, 0};

        {   // h0
            short8v Bf[5];
#pragma unroll
            for (int kt = 0; kt < 4; ++kt)
                Bf[kt] = ldw8(W_h + (size_t)colb * 144 + kt * 32 + 8 * q);
            Bf[4] = (q < 2) ? ldw8(W_h + (size_t)colb * 144 + 128 + 8 * q) : zfrag;
            f32x4 ahA = {b_h[colb], b_h[colb], b_h[colb], b_h[colb]};
            f32x4 ahB = ahA;
            ahA = MFMA(A0A, Bf[0], ahA);  ahB = MFMA(A0B, Bf[0], ahB);
            ahA = MFMA(A1A, Bf[1], ahA);  ahB = MFMA(A1B, Bf[1], ahB);
            ahA = MFMA(N0A, Bf[2], ahA);  ahB = MFMA(N0B, Bf[2], ahB);
            ahA = MFMA(N1A, Bf[3], ahA);  ahB = MFMA(N1B, Bf[3], ahB);
            ahA = MFMA(N2A, Bf[4], ahA);  ahB = MFMA(N2B, Bf[4], ahB);
            unsigned short* nh0 = &hbuf[0][cur ^ 1][0];
            unsigned short* nh1 = &hbuf[1][cur ^ 1][0];
            H_STORE4(nh0, ahA[0], ahA[1], ahA[2], ahA[3]);
            H_STORE4(nh1, ahB[0], ahB[1], ahB[2], ahB[3]);
        }
        {   // c0
            short8v Bf[5];
#pragma unroll
            for (int kt = 0; kt < 4; ++kt)
                Bf[kt] = ldw8(W_c + (size_t)colb * 144 + kt * 32 + 8 * q);
            Bf[4] = (q < 2) ? ldw8(W_c + (size_t)colb * 144 + 128 + 8 * q) : zfrag;
            f32x4 acA = {b_c[colb], b_c[colb], b_c[colb], b_c[colb]};
            f32x4 acB = acA;
            acA = MFMA(A0A, Bf[0], acA);  acB = MFMA(A0B, Bf[0], acB);
            acA = MFMA(A1A, Bf[1], acA);  acB = MFMA(A1B, Bf[1], acB);
            acA = MFMA(N0A, Bf[2], acA);  acB = MFMA(N0B, Bf[2], acB);
            acA = MFMA(N1A, Bf[3], acA);  acB = MFMA(N1B, Bf[3], acB);
            acA = MFMA(N2A, Bf[4], acA);  acB = MFMA(N2B, Bf[4], acB);
#pragma unroll
            for (int r = 0; r < 4; ++r) { c[0][r] = acA[r]; c[1][r] = acB[r]; }
        }
        __syncthreads();
        cur ^= 1;
    }

    // ==================== decoder (1 barrier/step) ====================
#pragma unroll 1
    for (int t = 0; t < PRED_LEN; ++t) {
        const short8v H1A = *(const short8v*)(&hbuf[0][cur][jm * 72 + 8 * q]);
        const short8v H2A = *(const short8v*)(&hbuf[0][cur][jm * 72 + 32 + 8 * q]);
        const short8v H1B = *(const short8v*)(&hbuf[1][cur][jm * 72 + 8 * q]);
        const short8v H2B = *(const short8v*)(&hbuf[1][cur][jm * 72 + 32 + 8 * q]);

        f32x4 gA[4], gB[4];
        float xA0, xA1, xB0, xB1;
        if (t == 0) {
#pragma unroll
            for (int t4 = 0; t4 < 4; ++t4) {
                f32x4 a = {bias_g[t4], bias_g[t4], bias_g[t4], bias_g[t4]};
                f32x4 b = a;
                a = MFMA(H1A, Bw[1][t4], a);  b = MFMA(H1B, Bw[1][t4], b);
                a = MFMA(H2A, Bw[2][t4], a);  b = MFMA(H2B, Bw[2][t4], b);
                gA[t4] = a; gB[t4] = b;
            }
            xA0 = obs_l[jm * 40 + 38];        xA1 = obs_l[jm * 40 + 39];
            xB0 = obs_l[(16 + jm) * 40 + 38]; xB1 = obs_l[(16 + jm) * 40 + 39];
        } else {
            // y-MFMA first; 16 independent gate MFMAs cover its latency
            f32x4 yA = {0.f, 0.f, 0.f, 0.f}, yB = {0.f, 0.f, 0.f, 0.f};
            yA = MFMA(H1A, Bo0, yA);  yB = MFMA(H1B, Bo0, yB);
            yA = MFMA(H2A, Bo1, yA);  yB = MFMA(H2B, Bo1, yB);
#pragma unroll
            for (int t4 = 0; t4 < 4; ++t4) {
                f32x4 a = {bias_g[t4], bias_g[t4], bias_g[t4], bias_g[t4]};
                f32x4 b = a;
                a = MFMA(H1A, Bw[1][t4], a);  b = MFMA(H1B, Bw[1][t4], b);
                a = MFMA(H2A, Bw[2][t4], a);  b = MFMA(H2B, Bw[2][t4], b);
                gA[t4] = a; gB[t4] = b;
            }
            if (jm < 2) {
#pragma unroll
                for (int r = 0; r < 4; ++r) {
                    y_lds[w][0][4 * q + r][jm] = yA[r];
                    y_lds[w][1][4 * q + r][jm] = yB[r];
                }
            }
            if (w == 0 && jm < 2) {
                const float bo = (jm == 0) ? bo0 : bo1;
#pragma unroll
                for (int r = 0; r < 4; ++r) {
                    y_hist[(4 * q + r) * 60 + (t - 1) * 2 + jm]      = yA[r] + bo;
                    y_hist[(16 + 4 * q + r) * 60 + (t - 1) * 2 + jm] = yB[r] + bo;
                }
            }
            asm volatile("s_waitcnt lgkmcnt(0)" ::: "memory");
            __builtin_amdgcn_sched_barrier(0);
            xA0 = y_lds[w][0][jm][0] + bo0;  xA1 = y_lds[w][0][jm][1] + bo1;
            xB0 = y_lds[w][1][jm][0] + bo0;  xB1 = y_lds[w][1][jm][1] + bo1;
        }
        const short8v AeA = embed8(xA0, xA1, wE0, wE1, bE);
        const short8v AeB = embed8(xB0, xB1, wE0, wE1, bE);
#pragma unroll
        for (int t4 = 0; t4 < 4; ++t4) {
            gA[t4] = MFMA(AeA, Bw[0][t4], gA[t4]);
            gB[t4] = MFMA(AeB, Bw[0][t4], gB[t4]);
        }
#pragma unroll
        for (int p = 0; p < 2; ++p) {
            unsigned short* nh = &hbuf[p][cur ^ 1][0];
            float hv[4];
#pragma unroll
            for (int r = 0; r < 4; ++r) {
                const f32x4* g = (p == 0) ? gA : gB;
                hv[r] = lstm_h(g[0][r], g[1][r], g[2][r], g[3][r], c[p][r]);
            }
            H_STORE4(nh, hv[0], hv[1], hv[2], hv[3]);
        }
        __syncthreads();   // hbuf[cur^1] + y_hist visible
        cur ^= 1;
    }

    // ==================== final y (pred 29) from h_30 ====================
    {
        const short8v H1A = *(const short8v*)(&hbuf[0][cur][jm * 72 + 8 * q]);
        const short8v H2A = *(const short8v*)(&hbuf[0][cur][jm * 72 + 32 + 8 * q]);
        const short8v H1B = *(const short8v*)(&hbuf[1][cur][jm * 72 + 8 * q]);
        const short8v H2B = *(const short8v*)(&hbuf[1][cur][jm * 72 + 32 + 8 * q]);
        f32x4 yA = {0.f, 0.f, 0.f, 0.f}, yB = {0.f, 0.f, 0.f, 0.f};
        yA = MFMA(H1A, Bo0, yA);  yB = MFMA(H1B, Bo0, yB);
        yA = MFMA(H2A, Bo1, yA);  yB = MFMA(H2B, Bo1, yB);
        if (w == 0 && jm < 2) {
            const float bo = (jm == 0) ? bo0 : bo1;
#pragma unroll
            for (int r = 0; r < 4; ++r) {
                y_hist[(4 * q + r) * 60 + (PRED_LEN - 1) * 2 + jm]      = yA[r] + bo;
                y_hist[(16 + 4 * q + r) * 60 + (PRED_LEN - 1) * 2 + jm] = yB[r] + bo;
            }
        }
        __syncthreads();
        float* op = out + (size_t)bb * 60;
        for (int k2 = id; k2 < 1920; k2 += 256) op[k2] = y_hist[k2];
    }
#undef H_STORE4
}

extern "C" void kernel_launch(void* const* d_in, const int* in_sizes, int n_in,
                              void* d_out, int out_size, void* d_ws, size_t ws_size,
                              hipStream_t stream) {
    (void)in_sizes; (void)n_in; (void)d_ws; (void)ws_size; (void)out_size;
    const float* obs    = (const float*)d_in[0];
    const float* noise  = (const float*)d_in[1];
    const float* scene  = (const float*)d_in[2];
    const float* W_emb  = (const float*)d_in[3];
    const float* b_emb  = (const float*)d_in[4];
    const float* Wih_e  = (const float*)d_in[5];
    const float* Whh_e  = (const float*)d_in[6];
    const float* b_e    = (const float*)d_in[7];
    const float* W_h    = (const float*)d_in[8];
    const float* b_h    = (const float*)d_in[9];
    const float* W_c    = (const float*)d_in[10];
    const float* b_c    = (const float*)d_in[11];
    const float* Wih_d  = (const float*)d_in[12];
    const float* Whh_d  = (const float*)d_in[13];
    const float* b_d    = (const float*)d_in[14];
    const float* W_out  = (const float*)d_in[15];
    const float* b_out  = (const float*)d_in[16];
    float* out = (float*)d_out;

    dim3 grid(65536 / 32), block(256);
    hipLaunchKernelGGL(traj_mfma, grid, block, 0, stream,
                       obs, noise, scene, W_emb, b_emb,
                       Wih_e, Whh_e, b_e, W_h, b_h, W_c, b_c,
                       Wih_d, Whh_d, b_d, W_out, b_out, out);
}

// Round 17
// 315.563 us; speedup vs baseline: 1.4298x; 1.0454x over previous
//
#include <hip/hip_runtime.h>
#include <cstddef>

#define OBS_LEN  20
#define PRED_LEN 30

typedef __attribute__((ext_vector_type(8))) short short8v;  // 8 bf16 (4 VGPRs)
typedef __attribute__((ext_vector_type(4))) float f32x4;

// branchless RNE f32->bf16 (no libcall) — cold paths only
__device__ __forceinline__ unsigned short f2bf_rne(float x) {
    const unsigned u = __builtin_bit_cast(unsigned, x);
    return (unsigned short)((u + 0x7FFFu + ((u >> 16) & 1u)) >> 16);
}
// packed f32x2 -> bf16x2 in ONE VALU inst (RNE on gfx950)
__device__ __forceinline__ unsigned cvt_pk_bf16(float lo, float hi) {
    unsigned d;
    asm("v_cvt_pk_bf16_f32 %0, %1, %2" : "=v"(d) : "v"(lo), "v"(hi));
    return d;
}

// gate prescales: i,f,o -> -log2e ; g -> -2log2e (folded into weights)
#define GS0 -1.442695041f
#define GS2 -2.885390082f

// Fused-rcp LSTM nonlinearity: 8 trans (5 exp2 + 3 rcp) per output.
__device__ __forceinline__ float lstm_h(float yi, float yf, float yg, float yo,
                                        float& c) {
    const float Ei = __builtin_amdgcn_exp2f(yi);
    const float Ef = __builtin_amdgcn_exp2f(yf);
    const float Eg = __builtin_amdgcn_exp2f(fminf(yg, 126.0f));
    const float Eo = __builtin_amdgcn_exp2f(yo);
    const float fg = __builtin_amdgcn_rcpf(1.0f + Ef);
    const float ig = (1.0f - Eg) *
                     __builtin_amdgcn_rcpf((1.0f + Ei) * (1.0f + Eg));
    const float cn = fmaf(fg, c, ig);
    c = cn;
    const float Ec = __builtin_amdgcn_exp2f(fminf(cn * GS2, 126.0f));
    return (1.0f - Ec) * __builtin_amdgcn_rcpf((1.0f + Eo) * (1.0f + Ec));
}

// weight-row load -> bf16x8 fragment, scaled by s before conversion (cold)
__device__ __forceinline__ short8v ldw8s(const float* __restrict__ p, float s) {
    const float4 a = *(const float4*)(p);
    const float4 b = *(const float4*)(p + 4);
    uint4 w;
    w.x = (unsigned)f2bf_rne(a.x * s) | ((unsigned)f2bf_rne(a.y * s) << 16);
    w.y = (unsigned)f2bf_rne(a.z * s) | ((unsigned)f2bf_rne(a.w * s) << 16);
    w.z = (unsigned)f2bf_rne(b.x * s) | ((unsigned)f2bf_rne(b.y * s) << 16);
    w.w = (unsigned)f2bf_rne(b.z * s) | ((unsigned)f2bf_rne(b.w * s) << 16);
    return __builtin_bit_cast(short8v, w);
}
__device__ __forceinline__ short8v ldw8(const float* __restrict__ p) {
    return ldw8s(p, 1.0f);
}
// per-lane embed: 8 units (rows 8q..8q+7) -> A-fragment, cvt_pk packing
__device__ __forceinline__ short8v embed8(float x0, float x1,
        const float wE0[8], const float wE1[8], const float bE[8]) {
    float e[8];
#pragma unroll
    for (int j = 0; j < 8; ++j)
        e[j] = fmaxf(0.f, fmaf(wE0[j], x0, fmaf(wE1[j], x1, bE[j])));
    uint4 w;
    w.x = cvt_pk_bf16(e[0], e[1]);
    w.y = cvt_pk_bf16(e[2], e[3]);
    w.z = cvt_pk_bf16(e[4], e[5]);
    w.w = cvt_pk_bf16(e[6], e[7]);
    return __builtin_bit_cast(short8v, w);
}

#define MFMA(A, B, C) __builtin_amdgcn_mfma_f32_16x16x32_bf16((A), (B), (C), 0, 0, 0)

__device__ __forceinline__ void load_gates(short8v Bw[3][4], float bias_g[4],
        const float* __restrict__ Wih, const float* __restrict__ Whh,
        const float* __restrict__ bias, int colb, int q) {
    const float GS[4] = {GS0, GS0, GS2, GS0};
#pragma unroll
    for (int t = 0; t < 4; ++t) {
        const int row = t * 64 + colb;
        const float s = GS[t];
        Bw[0][t] = ldw8s(Wih + row * 32 + 8 * q, s);
        Bw[1][t] = ldw8s(Whh + row * 64 + 8 * q, s);
        Bw[2][t] = ldw8s(Whh + row * 64 + 32 + 8 * q, s);
        bias_g[t] = bias[row] * s;
    }
}

// R15/R16 single-tile NaN'd twice (cause not identified) -> REVERT to the
// R14 2-tile kernel (329.9us, passed). One bounded-risk change vs R14: the
// decoder overlay (load_gates dec + Bo, 56 regs) now loads AFTER the cond
// phase instead of before it -> 56 fewer live regs at the cond Bf[5] peak
// -> less (256,3)-induced cold spill. Pure code motion, no math/sync change.
extern "C" __global__ void __launch_bounds__(256, 3)
traj_mfma(const float* __restrict__ obs,   const float* __restrict__ noise,
          const float* __restrict__ scene,
          const float* __restrict__ W_emb, const float* __restrict__ b_emb,
          const float* __restrict__ Wih_e, const float* __restrict__ Whh_e, const float* __restrict__ b_e,
          const float* __restrict__ W_h,   const float* __restrict__ b_h,
          const float* __restrict__ W_c,   const float* __restrict__ b_c,
          const float* __restrict__ Wih_d, const float* __restrict__ Whh_d, const float* __restrict__ b_d,
          const float* __restrict__ W_out, const float* __restrict__ b_out,
          float* __restrict__ out)
{
    __shared__ __align__(16) unsigned short hbuf[2][2][1152]; // [tile][buf] 16x72 bf16
    __shared__ __align__(16) float uni[2816];                 // obs_l | ns | y_hist union
    __shared__ __align__(16) float y_lds[4][2][16][2];        // per-WAVE y copy

    const int id = threadIdx.x;
    const int l    = id & 63;
    const int w    = id >> 6;        // wave = gate-column slice
    const int q    = l >> 4;
    const int jm   = l & 15;
    const int colb = w * 16 + jm;    // hidden j in [0,64)
    const int bb   = blockIdx.x * 32;

    float* obs_l = uni;                                   // 1280 f32
    unsigned short* ns = (unsigned short*)(uni + 1280);   // 3072 bf16
    float* y_hist = uni;                                  // 1920 f32 (aliases)

    // ---------------- overlay gate-weight registers (one phase at a time) ----
    short8v Bw[3][4];
    float bias_g[4];
    load_gates(Bw, bias_g, Wih_e, Whh_e, b_e, colb, q);   // encoder set

    // per-lane embed weights: units 8q..8q+7
    float wE0[8], wE1[8], bE[8];
#pragma unroll
    for (int j = 0; j < 8; ++j) {
        wE0[j] = W_emb[(8 * q + j) * 2];
        wE1[j] = W_emb[(8 * q + j) * 2 + 1];
        bE[j]  = b_emb[8 * q + j];
    }
    const float bo0 = b_out[0], bo1 = b_out[1];

    // init h=0, stage obs (32 rows)
    {
        unsigned* hz = (unsigned*)&hbuf[0][0][0];
        for (int k2 = id; k2 < 2304; k2 += 256) hz[k2] = 0u;
        for (int k2 = id; k2 < 1280; k2 += 256) obs_l[k2] = obs[(size_t)bb * 40 + k2];
    }
    float c[2][4];
#pragma unroll
    for (int p = 0; p < 2; ++p)
#pragma unroll
        for (int r = 0; r < 4; ++r) c[p][r] = 0.f;
    __syncthreads();

    int cur = 0;

    // packed h-store: 4 rows (stride 72 shorts), 2 cvt_pk + 4 b16 stores
#define H_STORE4(nh_, hv0, hv1, hv2, hv3)                         \
    {                                                             \
        const unsigned p01 = cvt_pk_bf16((hv0), (hv1));           \
        const unsigned p23 = cvt_pk_bf16((hv2), (hv3));           \
        unsigned short* b_ = (nh_) + (4 * q) * 72 + colb;         \
        b_[0]       = (unsigned short)p01;                        \
        b_[72]      = (unsigned short)(p01 >> 16);                \
        b_[144]     = (unsigned short)p23;                        \
        b_[216]     = (unsigned short)(p23 >> 16);                \
    }

    // ==================== encoder (1 barrier/step) ====================
#pragma unroll 1
    for (int t = 0; t < OBS_LEN; ++t) {
        const short8v H1A = *(const short8v*)(&hbuf[0][cur][jm * 72 + 8 * q]);
        const short8v H2A = *(const short8v*)(&hbuf[0][cur][jm * 72 + 32 + 8 * q]);
        const short8v H1B = *(const short8v*)(&hbuf[1][cur][jm * 72 + 8 * q]);
        const short8v H2B = *(const short8v*)(&hbuf[1][cur][jm * 72 + 32 + 8 * q]);

        // H-gate MFMAs first; embed overlaps their latency
        f32x4 gA[4], gB[4];
#pragma unroll
        for (int t4 = 0; t4 < 4; ++t4) {
            f32x4 a = {bias_g[t4], bias_g[t4], bias_g[t4], bias_g[t4]};
            f32x4 b = a;
            a = MFMA(H1A, Bw[1][t4], a);  b = MFMA(H1B, Bw[1][t4], b);
            a = MFMA(H2A, Bw[2][t4], a);  b = MFMA(H2B, Bw[2][t4], b);
            gA[t4] = a; gB[t4] = b;
        }
        const short8v AeA = embed8(obs_l[jm * 40 + 2 * t], obs_l[jm * 40 + 2 * t + 1],
                                   wE0, wE1, bE);
        const short8v AeB = embed8(obs_l[(16 + jm) * 40 + 2 * t], obs_l[(16 + jm) * 40 + 2 * t + 1],
                                   wE0, wE1, bE);
#pragma unroll
        for (int t4 = 0; t4 < 4; ++t4) {
            gA[t4] = MFMA(AeA, Bw[0][t4], gA[t4]);
            gB[t4] = MFMA(AeB, Bw[0][t4], gB[t4]);
        }
#pragma unroll
        for (int p = 0; p < 2; ++p) {
            unsigned short* nh = &hbuf[p][cur ^ 1][0];
            float hv[4];
#pragma unroll
            for (int r = 0; r < 4; ++r) {
                const f32x4* g = (p == 0) ? gA : gB;
                hv[r] = lstm_h(g[0][r], g[1][r], g[2][r], g[3][r], c[p][r]);
            }
            H_STORE4(nh, hv[0], hv[1], hv[2], hv[3]);
        }
        __syncthreads();
        cur ^= 1;
    }

    // ==================== cond -> decoder init ====================
    {
        {   // stage [noise | scene | 0] as bf16 into ns (union region)
            const int i2 = id >> 4, cb = (id & 15) * 6;
#pragma unroll
            for (int p = 0; p < 2; ++p) {
                const int row = bb + p * 16 + i2;
#pragma unroll
                for (int cc = 0; cc < 6; ++cc) {
                    const int col = cb + cc;
                    float v;
                    if (col < 16)      v = noise[(size_t)row * 16 + col];
                    else if (col < 80) v = scene[(size_t)row * 64 + (col - 16)];
                    else               v = 0.f;
                    ns[p * 1536 + i2 * 96 + col] = f2bf_rne(v);
                }
            }
        }
        __syncthreads();

        const short8v A0A = *(const short8v*)(&hbuf[0][cur][jm * 72 + 8 * q]);
        const short8v A1A = *(const short8v*)(&hbuf[0][cur][jm * 72 + 32 + 8 * q]);
        const short8v A0B = *(const short8v*)(&hbuf[1][cur][jm * 72 + 8 * q]);
        const short8v A1B = *(const short8v*)(&hbuf[1][cur][jm * 72 + 32 + 8 * q]);
        const short8v N0A = *(const short8v*)(ns + jm * 96 + 8 * q);
        const short8v N1A = *(const short8v*)(ns + jm * 96 + 32 + 8 * q);
        const short8v N2A = *(const short8v*)(ns + jm * 96 + 64 + 8 * q);
        const short8v N0B = *(const short8v*)(ns + 1536 + jm * 96 + 8 * q);
        const short8v N1B = *(const short8v*)(ns + 1536 + jm * 96 + 32 + 8 * q);
        const short8v N2B = *(const short8v*)(ns + 1536 + jm * 96 + 64 + 8 * q);
        const short8v zfrag = {0, 0, 0, 0, 0, 0, 0, 0};

        {   // h0
            short8v Bf[5];
#pragma unroll
            for (int kt = 0; kt < 4; ++kt)
                Bf[kt] = ldw8(W_h + (size_t)colb * 144 + kt * 32 + 8 * q);
            Bf[4] = (q < 2) ? ldw8(W_h + (size_t)colb * 144 + 128 + 8 * q) : zfrag;
            f32x4 ahA = {b_h[colb], b_h[colb], b_h[colb], b_h[colb]};
            f32x4 ahB = ahA;
            ahA = MFMA(A0A, Bf[0], ahA);  ahB = MFMA(A0B, Bf[0], ahB);
            ahA = MFMA(A1A, Bf[1], ahA);  ahB = MFMA(A1B, Bf[1], ahB);
            ahA = MFMA(N0A, Bf[2], ahA);  ahB = MFMA(N0B, Bf[2], ahB);
            ahA = MFMA(N1A, Bf[3], ahA);  ahB = MFMA(N1B, Bf[3], ahB);
            ahA = MFMA(N2A, Bf[4], ahA);  ahB = MFMA(N2B, Bf[4], ahB);
            unsigned short* nh0 = &hbuf[0][cur ^ 1][0];
            unsigned short* nh1 = &hbuf[1][cur ^ 1][0];
            H_STORE4(nh0, ahA[0], ahA[1], ahA[2], ahA[3]);
            H_STORE4(nh1, ahB[0], ahB[1], ahB[2], ahB[3]);
        }
        {   // c0
            short8v Bf[5];
#pragma unroll
            for (int kt = 0; kt < 4; ++kt)
                Bf[kt] = ldw8(W_c + (size_t)colb * 144 + kt * 32 + 8 * q);
            Bf[4] = (q < 2) ? ldw8(W_c + (size_t)colb * 144 + 128 + 8 * q) : zfrag;
            f32x4 acA = {b_c[colb], b_c[colb], b_c[colb], b_c[colb]};
            f32x4 acB = acA;
            acA = MFMA(A0A, Bf[0], acA);  acB = MFMA(A0B, Bf[0], acB);
            acA = MFMA(A1A, Bf[1], acA);  acB = MFMA(A1B, Bf[1], acB);
            acA = MFMA(N0A, Bf[2], acA);  acB = MFMA(N0B, Bf[2], acB);
            acA = MFMA(N1A, Bf[3], acA);  acB = MFMA(N1B, Bf[3], acB);
            acA = MFMA(N2A, Bf[4], acA);  acB = MFMA(N2B, Bf[4], acB);
#pragma unroll
            for (int r = 0; r < 4; ++r) { c[0][r] = acA[r]; c[1][r] = acB[r]; }
        }
        __syncthreads();
        cur ^= 1;
    }

    // -------- swap overlay to decoder weights (AFTER cond: Bf dead now, so
    // peak register pressure excludes this 56-reg set -> less spill) --------
    load_gates(Bw, bias_g, Wih_d, Whh_d, b_d, colb, q);
    short8v Bo0, Bo1;
    {
        const short8v z = {0, 0, 0, 0, 0, 0, 0, 0};
        if (jm < 2) {
            Bo0 = ldw8(W_out + jm * 64 + 8 * q);
            Bo1 = ldw8(W_out + jm * 64 + 32 + 8 * q);
        } else { Bo0 = z; Bo1 = z; }
    }

    // ==================== decoder (1 barrier/step) ====================
#pragma unroll 1
    for (int t = 0; t < PRED_LEN; ++t) {
        const short8v H1A = *(const short8v*)(&hbuf[0][cur][jm * 72 + 8 * q]);
        const short8v H2A = *(const short8v*)(&hbuf[0][cur][jm * 72 + 32 + 8 * q]);
        const short8v H1B = *(const short8v*)(&hbuf[1][cur][jm * 72 + 8 * q]);
        const short8v H2B = *(const short8v*)(&hbuf[1][cur][jm * 72 + 32 + 8 * q]);

        f32x4 gA[4], gB[4];
        float xA0, xA1, xB0, xB1;
        if (t == 0) {
#pragma unroll
            for (int t4 = 0; t4 < 4; ++t4) {
                f32x4 a = {bias_g[t4], bias_g[t4], bias_g[t4], bias_g[t4]};
                f32x4 b = a;
                a = MFMA(H1A, Bw[1][t4], a);  b = MFMA(H1B, Bw[1][t4], b);
                a = MFMA(H2A, Bw[2][t4], a);  b = MFMA(H2B, Bw[2][t4], b);
                gA[t4] = a; gB[t4] = b;
            }
            xA0 = obs_l[jm * 40 + 38];        xA1 = obs_l[jm * 40 + 39];
            xB0 = obs_l[(16 + jm) * 40 + 38]; xB1 = obs_l[(16 + jm) * 40 + 39];
        } else {
            // y-MFMA first; 16 independent gate MFMAs cover its latency
            f32x4 yA = {0.f, 0.f, 0.f, 0.f}, yB = {0.f, 0.f, 0.f, 0.f};
            yA = MFMA(H1A, Bo0, yA);  yB = MFMA(H1B, Bo0, yB);
            yA = MFMA(H2A, Bo1, yA);  yB = MFMA(H2B, Bo1, yB);
#pragma unroll
            for (int t4 = 0; t4 < 4; ++t4) {
                f32x4 a = {bias_g[t4], bias_g[t4], bias_g[t4], bias_g[t4]};
                f32x4 b = a;
                a = MFMA(H1A, Bw[1][t4], a);  b = MFMA(H1B, Bw[1][t4], b);
                a = MFMA(H2A, Bw[2][t4], a);  b = MFMA(H2B, Bw[2][t4], b);
                gA[t4] = a; gB[t4] = b;
            }
            if (jm < 2) {
#pragma unroll
                for (int r = 0; r < 4; ++r) {
                    y_lds[w][0][4 * q + r][jm] = yA[r];
                    y_lds[w][1][4 * q + r][jm] = yB[r];
                }
            }
            if (w == 0 && jm < 2) {
                const float bo = (jm == 0) ? bo0 : bo1;
#pragma unroll
                for (int r = 0; r < 4; ++r) {
                    y_hist[(4 * q + r) * 60 + (t - 1) * 2 + jm]      = yA[r] + bo;
                    y_hist[(16 + 4 * q + r) * 60 + (t - 1) * 2 + jm] = yB[r] + bo;
                }
            }
            asm volatile("s_waitcnt lgkmcnt(0)" ::: "memory");
            __builtin_amdgcn_sched_barrier(0);
            xA0 = y_lds[w][0][jm][0] + bo0;  xA1 = y_lds[w][0][jm][1] + bo1;
            xB0 = y_lds[w][1][jm][0] + bo0;  xB1 = y_lds[w][1][jm][1] + bo1;
        }
        const short8v AeA = embed8(xA0, xA1, wE0, wE1, bE);
        const short8v AeB = embed8(xB0, xB1, wE0, wE1, bE);
#pragma unroll
        for (int t4 = 0; t4 < 4; ++t4) {
            gA[t4] = MFMA(AeA, Bw[0][t4], gA[t4]);
            gB[t4] = MFMA(AeB, Bw[0][t4], gB[t4]);
        }
#pragma unroll
        for (int p = 0; p < 2; ++p) {
            unsigned short* nh = &hbuf[p][cur ^ 1][0];
            float hv[4];
#pragma unroll
            for (int r = 0; r < 4; ++r) {
                const f32x4* g = (p == 0) ? gA : gB;
                hv[r] = lstm_h(g[0][r], g[1][r], g[2][r], g[3][r], c[p][r]);
            }
            H_STORE4(nh, hv[0], hv[1], hv[2], hv[3]);
        }
        __syncthreads();   // hbuf[cur^1] + y_hist visible
        cur ^= 1;
    }

    // ==================== final y (pred 29) from h_30 ====================
    {
        const short8v H1A = *(const short8v*)(&hbuf[0][cur][jm * 72 + 8 * q]);
        const short8v H2A = *(const short8v*)(&hbuf[0][cur][jm * 72 + 32 + 8 * q]);
        const short8v H1B = *(const short8v*)(&hbuf[1][cur][jm * 72 + 8 * q]);
        const short8v H2B = *(const short8v*)(&hbuf[1][cur][jm * 72 + 32 + 8 * q]);
        f32x4 yA = {0.f, 0.f, 0.f, 0.f}, yB = {0.f, 0.f, 0.f, 0.f};
        yA = MFMA(H1A, Bo0, yA);  yB = MFMA(H1B, Bo0, yB);
        yA = MFMA(H2A, Bo1, yA);  yB = MFMA(H2B, Bo1, yB);
        if (w == 0 && jm < 2) {
            const float bo = (jm == 0) ? bo0 : bo1;
#pragma unroll
            for (int r = 0; r < 4; ++r) {
                y_hist[(4 * q + r) * 60 + (PRED_LEN - 1) * 2 + jm]      = yA[r] + bo;
                y_hist[(16 + 4 * q + r) * 60 + (PRED_LEN - 1) * 2 + jm] = yB[r] + bo;
            }
        }
        __syncthreads();
        float* op = out + (size_t)bb * 60;
        for (int k2 = id; k2 < 1920; k2 += 256) op[k2] = y_hist[k2];
    }
#undef H_STORE4
}

extern "C" void kernel_launch(void* const* d_in, const int* in_sizes, int n_in,
                              void* d_out, int out_size, void* d_ws, size_t ws_size,
                              hipStream_t stream) {
    (void)in_sizes; (void)n_in; (void)d_ws; (void)ws_size; (void)out_size;
    const float* obs    = (const float*)d_in[0];
    const float* noise  = (const float*)d_in[1];
    const float* scene  = (const float*)d_in[2];
    const float* W_emb  = (const float*)d_in[3];
    const float* b_emb  = (const float*)d_in[4];
    const float* Wih_e  = (const float*)d_in[5];
    const float* Whh_e  = (const float*)d_in[6];
    const float* b_e    = (const float*)d_in[7];
    const float* W_h    = (const float*)d_in[8];
    const float* b_h    = (const float*)d_in[9];
    const float* W_c    = (const float*)d_in[10];
    const float* b_c    = (const float*)d_in[11];
    const float* Wih_d  = (const float*)d_in[12];
    const float* Whh_d  = (const float*)d_in[13];
    const float* b_d    = (const float*)d_in[14];
    const float* W_out  = (const float*)d_in[15];
    const float* b_out  = (const float*)d_in[16];
    float* out = (float*)d_out;

    dim3 grid(65536 / 32), block(256);
    hipLaunchKernelGGL(traj_mfma, grid, block, 0, stream,
                       obs, noise, scene, W_emb, b_emb,
                       Wih_e, Whh_e, b_e, W_h, b_h, W_c, b_c,
                       Wih_d, Whh_d, b_d, W_out, b_out, out);
}